// Round 1
// baseline (231.233 us; speedup 1.0000x reference)
//
#include <hip/hip_runtime.h>
#include <hip/hip_bf16.h>

// Problem constants
#define N 1024
#define NF 27
#define EF 17
#define H 128
#define HEADS 4
#define HD 32

// ---------------- Encoder: enc = relu(nf@w1+b1)@w2+b2 ----------------
__global__ __launch_bounds__(128) void k_encoder(
    const float* __restrict__ nf, const float* __restrict__ w1, const float* __restrict__ b1,
    const float* __restrict__ w2, const float* __restrict__ b2, float* __restrict__ enc)
{
  __shared__ float s_nf[NF];
  __shared__ float s_h1[H];
  const int i = blockIdx.x, t = threadIdx.x;
  if (t < NF) s_nf[t] = nf[i * NF + t];
  __syncthreads();
  float h = b1[t];
  #pragma unroll
  for (int f = 0; f < NF; ++f) h = fmaf(s_nf[f], w1[f * H + t], h);
  h = fmaxf(h, 0.f);
  s_h1[t] = h;
  __syncthreads();
  float acc = b2[t];
  #pragma unroll 8
  for (int k = 0; k < H; ++k) acc = fmaf(s_h1[k], w2[k * H + t], acc);
  enc[i * H + t] = acc;
}

// ---------------- Projections: q, k, sa_p, sb_p^T, sa_c, sb_c^T ----------------
__global__ __launch_bounds__(256) void k_proj(
    const float* __restrict__ enc,
    const float* __restrict__ ipw, const float* __restrict__ ipb,
    const float* __restrict__ pw1, const float* __restrict__ cw1,
    float* __restrict__ q, float* __restrict__ kk,
    float* __restrict__ sa_p, float* __restrict__ sb_pT,
    float* __restrict__ sa_c, float* __restrict__ sb_cT)
{
  __shared__ float s_e[H];
  const int i = blockIdx.x, t = threadIdx.x;
  if (t < H) s_e[t] = enc[i * H + t];
  __syncthreads();
  for (int c = t; c < 640; c += 256) {
    float acc;
    if (c < 256) {
      // q (cols 0..127) and k (cols 128..255) of in_proj
      acc = ipb[c];
      const float* wcol = ipw + c;
      #pragma unroll 8
      for (int k = 0; k < H; ++k) acc = fmaf(s_e[k], wcol[k * 384], acc);
      if (c < 128) q[i * H + c] = acc;
      else         kk[i * H + (c - 128)] = acc;
    } else if (c < 512) {
      // sa_p (pred_w1 rows 0..127), sb_p (rows 128..255)
      const int cc = (c < 384) ? (c - 256) : (c - 384);
      const float* wcol = (c < 384) ? (pw1 + cc) : (pw1 + 128 * H + cc);
      acc = 0.f;
      #pragma unroll 8
      for (int k = 0; k < H; ++k) acc = fmaf(s_e[k], wcol[k * H], acc);
      if (c < 384) sa_p[i * H + cc] = acc;
      else         sb_pT[cc * N + i] = acc;  // transposed for coalesced pair-kernel reads
    } else {
      // sa_c (cls_w1 rows 0..127), sb_c (rows 128..255), width 64
      const int cc = (c < 576) ? (c - 512) : (c - 576);
      const float* wcol = (c < 576) ? (cw1 + cc) : (cw1 + 128 * 64 + cc);
      acc = 0.f;
      #pragma unroll 8
      for (int k = 0; k < H; ++k) acc = fmaf(s_e[k], wcol[k * 64], acc);
      if (c < 576) sa_c[i * 64 + cc] = acc;
      else         sb_cT[cc * N + i] = acc;
    }
  }
}

// ---------------- Attention weights: softmax(QK^T/sqrt(hd)) mean over heads ----------------
__global__ __launch_bounds__(256) void k_attn(
    const float* __restrict__ q, const float* __restrict__ kk, float* __restrict__ out0)
{
  __shared__ float s_q[H];
  __shared__ float s_s[HEADS * N];   // 16K floats = 64KB
  __shared__ float s_red[HEADS * 4];
  __shared__ float s_m[HEADS];
  __shared__ float s_inv[HEADS];
  const int i = blockIdx.x, t = threadIdx.x;
  if (t < H) s_q[t] = q[i * H + t];
  __syncthreads();
  const float scale = 0.17677669529663687f;  // 1/sqrt(32)
  for (int jj = 0; jj < 4; ++jj) {
    const int j = jj * 256 + t;
    const float4* krow = (const float4*)(kk + j * H);
    float sh[HEADS] = {0.f, 0.f, 0.f, 0.f};
    #pragma unroll
    for (int d4 = 0; d4 < 32; ++d4) {
      const float4 kv = krow[d4];
      const float4 qv = *(const float4*)(s_q + d4 * 4);
      sh[d4 >> 3] += qv.x * kv.x + qv.y * kv.y + qv.z * kv.z + qv.w * kv.w;
    }
    #pragma unroll
    for (int h = 0; h < HEADS; ++h) s_s[h * N + j] = sh[h] * scale;
  }
  __syncthreads();
  // per-head row max
  #pragma unroll
  for (int h = 0; h < HEADS; ++h) {
    float m = -1e30f;
    for (int j = t; j < N; j += 256) m = fmaxf(m, s_s[h * N + j]);
    for (int off = 32; off; off >>= 1) m = fmaxf(m, __shfl_down(m, off));
    if ((t & 63) == 0) s_red[h * 4 + (t >> 6)] = m;
  }
  __syncthreads();
  if (t < HEADS)
    s_m[t] = fmaxf(fmaxf(s_red[t * 4], s_red[t * 4 + 1]),
                   fmaxf(s_red[t * 4 + 2], s_red[t * 4 + 3]));
  __syncthreads();
  // per-head sum of exp
  #pragma unroll
  for (int h = 0; h < HEADS; ++h) {
    const float m = s_m[h];
    float s = 0.f;
    for (int j = t; j < N; j += 256) s += __expf(s_s[h * N + j] - m);
    for (int off = 32; off; off >>= 1) s += __shfl_down(s, off);
    if ((t & 63) == 0) s_red[h * 4 + (t >> 6)] = s;
  }
  __syncthreads();
  if (t < HEADS)
    s_inv[t] = 0.25f / (s_red[t * 4] + s_red[t * 4 + 1] + s_red[t * 4 + 2] + s_red[t * 4 + 3]);
  __syncthreads();
  for (int jj = 0; jj < 4; ++jj) {
    const int j = jj * 256 + t;
    float v = 0.f;
    #pragma unroll
    for (int h = 0; h < HEADS; ++h) v += __expf(s_s[h * N + j] - s_m[h]) * s_inv[h];
    out0[i * N + j] = v;
  }
}

// ---------------- Pairwise MLPs: edge features + edge probability ----------------
__global__ __launch_bounds__(256) void k_pair(
    const float* __restrict__ sa_p, const float* __restrict__ sb_pT,
    const float* __restrict__ pb1, const float* __restrict__ pw2, const float* __restrict__ pb2,
    const float* __restrict__ sa_c, const float* __restrict__ sb_cT,
    const float* __restrict__ cb1, const float* __restrict__ cw2, const float* __restrict__ cb2,
    float* __restrict__ out1, float* __restrict__ out2)
{
  __shared__ float s_ap[H];
  __shared__ float s_ac[64];
  const int b = blockIdx.x;
  const int i = b >> 2, jt = b & 3;
  const int t = threadIdx.x;
  const int j = jt * 256 + t;
  if (t < H) s_ap[t] = sa_p[i * H + t] + pb1[t];
  else if (t < H + 64) s_ac[t - H] = sa_c[i * 64 + (t - H)] + cb1[t - H];
  __syncthreads();

  float acc[EF];
  #pragma unroll
  for (int e = 0; e < EF; ++e) acc[e] = pb2[e];
  #pragma unroll 4
  for (int k = 0; k < H; ++k) {
    float h = s_ap[k] + sb_pT[k * N + j];
    h = fmaxf(h, 0.f);
    const float* w = pw2 + k * EF;   // uniform address -> scalar loads -> SGPR operands
    #pragma unroll
    for (int e = 0; e < EF; ++e) acc[e] = fmaf(h, w[e], acc[e]);
  }
  float* o2 = out2 + (size_t)(i * N + j) * EF;
  #pragma unroll
  for (int e = 0; e < EF; ++e) o2[e] = acc[e];

  float ac = 0.f;
  #pragma unroll 4
  for (int k = 0; k < 64; ++k) {
    const float h = fmaxf(s_ac[k] + sb_cT[k * N + j], 0.f);
    ac = fmaf(h, cw2[k], ac);
  }
  ac += cb2[0];
  out1[i * N + j] = 1.f / (1.f + __expf(-ac));
}

extern "C" void kernel_launch(void* const* d_in, const int* in_sizes, int n_in,
                              void* d_out, int out_size, void* d_ws, size_t ws_size,
                              hipStream_t stream) {
  const float* nf  = (const float*)d_in[0];
  const float* ew1 = (const float*)d_in[1];
  const float* eb1 = (const float*)d_in[2];
  const float* ew2 = (const float*)d_in[3];
  const float* eb2 = (const float*)d_in[4];
  const float* ipw = (const float*)d_in[5];
  const float* ipb = (const float*)d_in[6];
  const float* pw1 = (const float*)d_in[7];
  const float* pb1 = (const float*)d_in[8];
  const float* pw2 = (const float*)d_in[9];
  const float* pb2 = (const float*)d_in[10];
  const float* cw1 = (const float*)d_in[11];
  const float* cb1 = (const float*)d_in[12];
  const float* cw2 = (const float*)d_in[13];
  const float* cb2 = (const float*)d_in[14];

  float* ws = (float*)d_ws;
  float* enc   = ws;                 // 1024*128
  float* q     = ws + 131072;        // 1024*128
  float* kk    = ws + 262144;        // 1024*128
  float* sa_p  = ws + 393216;        // 1024*128
  float* sb_pT = ws + 524288;        // 128*1024 (transposed)
  float* sa_c  = ws + 655360;        // 1024*64
  float* sb_cT = ws + 720896;        // 64*1024 (transposed)

  float* out0 = (float*)d_out;             // attention_weights [1024*1024]
  float* out1 = out0 + N * N;              // edge_probabilities [1024*1024]
  float* out2 = out0 + 2 * N * N;          // predicted_edge_features [1024*1024*17]

  k_encoder<<<N, 128, 0, stream>>>(nf, ew1, eb1, ew2, eb2, enc);
  k_proj<<<N, 256, 0, stream>>>(enc, ipw, ipb, pw1, cw1, q, kk, sa_p, sb_pT, sa_c, sb_cT);
  k_attn<<<N, 256, 0, stream>>>(q, kk, out0);
  k_pair<<<N * 4, 256, 0, stream>>>(sa_p, sb_pT, pb1, pw2, pb2,
                                    sa_c, sb_cT, cb1, cw2, cb2, out1, out2);
}

// Round 2
// 125.972 us; speedup vs baseline: 1.8356x; 1.8356x over previous
//
#include <hip/hip_runtime.h>
#include <hip/hip_bf16.h>

// Problem constants
#define N 1024
#define NF 27
#define EF 17
#define H 128
#define HEADS 4
#define HD 32

// ---------------- Encoder: enc = relu(nf@w1+b1)@w2+b2 ----------------
__global__ __launch_bounds__(128) void k_encoder(
    const float* __restrict__ nf, const float* __restrict__ w1, const float* __restrict__ b1,
    const float* __restrict__ w2, const float* __restrict__ b2, float* __restrict__ enc)
{
  __shared__ float s_nf[NF];
  __shared__ float s_h1[H];
  const int i = blockIdx.x, t = threadIdx.x;
  if (t < NF) s_nf[t] = nf[i * NF + t];
  __syncthreads();
  float h = b1[t];
  #pragma unroll
  for (int f = 0; f < NF; ++f) h = fmaf(s_nf[f], w1[f * H + t], h);
  h = fmaxf(h, 0.f);
  s_h1[t] = h;
  __syncthreads();
  float acc = b2[t];
  #pragma unroll 8
  for (int k = 0; k < H; ++k) acc = fmaf(s_h1[k], w2[k * H + t], acc);
  enc[i * H + t] = acc;
}

// ---------------- Projections: q, kkT (transposed!), sa_p, sb_p^T, sa_c, sb_c^T ----------------
__global__ __launch_bounds__(256) void k_proj(
    const float* __restrict__ enc,
    const float* __restrict__ ipw, const float* __restrict__ ipb,
    const float* __restrict__ pw1, const float* __restrict__ cw1,
    float* __restrict__ q, float* __restrict__ kkT,
    float* __restrict__ sa_p, float* __restrict__ sb_pT,
    float* __restrict__ sa_c, float* __restrict__ sb_cT)
{
  __shared__ float s_e[H];
  const int i = blockIdx.x, t = threadIdx.x;
  if (t < H) s_e[t] = enc[i * H + t];
  __syncthreads();
  for (int c = t; c < 640; c += 256) {
    float acc;
    if (c < 256) {
      // q (cols 0..127) and k (cols 128..255) of in_proj
      acc = ipb[c];
      const float* wcol = ipw + c;
      #pragma unroll 8
      for (int k = 0; k < H; ++k) acc = fmaf(s_e[k], wcol[k * 384], acc);
      if (c < 128) q[i * H + c] = acc;
      else         kkT[(c - 128) * N + i] = acc;   // transposed for coalesced attn reads
    } else if (c < 512) {
      // sa_p (pred_w1 rows 0..127), sb_p (rows 128..255)
      const int cc = (c < 384) ? (c - 256) : (c - 384);
      const float* wcol = (c < 384) ? (pw1 + cc) : (pw1 + 128 * H + cc);
      acc = 0.f;
      #pragma unroll 8
      for (int k = 0; k < H; ++k) acc = fmaf(s_e[k], wcol[k * H], acc);
      if (c < 384) sa_p[i * H + cc] = acc;
      else         sb_pT[cc * N + i] = acc;  // transposed for coalesced pair-kernel reads
    } else {
      // sa_c (cls_w1 rows 0..127), sb_c (rows 128..255), width 64
      const int cc = (c < 576) ? (c - 512) : (c - 576);
      const float* wcol = (c < 576) ? (cw1 + cc) : (cw1 + 128 * 64 + cc);
      acc = 0.f;
      #pragma unroll 8
      for (int k = 0; k < H; ++k) acc = fmaf(s_e[k], wcol[k * 64], acc);
      if (c < 576) sa_c[i * 64 + cc] = acc;
      else         sb_cT[cc * N + i] = acc;
    }
  }
}

// ---------------- Attention weights: softmax(QK^T/sqrt(hd)) mean over heads ----------------
// 2 query rows per block; scores live in registers (float4 per (ti,head)).
__global__ __launch_bounds__(256) void k_attn(
    const float* __restrict__ q, const float* __restrict__ kkT, float* __restrict__ out0)
{
  __shared__ float s_q[2][H];
  __shared__ float s_redm[8][4];
  __shared__ float s_reds[8][4];
  const int i0 = blockIdx.x * 2, t = threadIdx.x;
  const int w = t >> 6, lane = t & 63;
  s_q[t >> 7][t & 127] = q[(i0 + (t >> 7)) * H + (t & 127)];
  __syncthreads();

  const float scale = 0.17677669529663687f;  // 1/sqrt(32)
  const float4* kT4 = (const float4*)kkT;    // [128][256] float4 rows
  float4 sc[2][4];

  #pragma unroll
  for (int h = 0; h < HEADS; ++h) {
    float4 a0 = {0.f, 0.f, 0.f, 0.f}, a1 = {0.f, 0.f, 0.f, 0.f};
    #pragma unroll 8
    for (int d = 0; d < HD; ++d) {
      const float4 kv = kT4[(h * HD + d) * 256 + t];
      const float q0 = s_q[0][h * HD + d], q1 = s_q[1][h * HD + d];
      a0.x = fmaf(q0, kv.x, a0.x); a0.y = fmaf(q0, kv.y, a0.y);
      a0.z = fmaf(q0, kv.z, a0.z); a0.w = fmaf(q0, kv.w, a0.w);
      a1.x = fmaf(q1, kv.x, a1.x); a1.y = fmaf(q1, kv.y, a1.y);
      a1.z = fmaf(q1, kv.z, a1.z); a1.w = fmaf(q1, kv.w, a1.w);
    }
    sc[0][h].x = a0.x * scale; sc[0][h].y = a0.y * scale;
    sc[0][h].z = a0.z * scale; sc[0][h].w = a0.w * scale;
    sc[1][h].x = a1.x * scale; sc[1][h].y = a1.y * scale;
    sc[1][h].z = a1.z * scale; sc[1][h].w = a1.w * scale;
  }

  // per-(ti,head) row max over 1024 (thread-local 4 -> 64-lane butterfly -> cross-wave)
  float m[2][4];
  #pragma unroll
  for (int ti = 0; ti < 2; ++ti)
    #pragma unroll
    for (int h = 0; h < HEADS; ++h) {
      float mm = fmaxf(fmaxf(sc[ti][h].x, sc[ti][h].y), fmaxf(sc[ti][h].z, sc[ti][h].w));
      for (int off = 32; off; off >>= 1) mm = fmaxf(mm, __shfl_xor(mm, off));
      if (lane == 0) s_redm[ti * 4 + h][w] = mm;
    }
  __syncthreads();
  #pragma unroll
  for (int ti = 0; ti < 2; ++ti)
    #pragma unroll
    for (int h = 0; h < HEADS; ++h) {
      const int idx = ti * 4 + h;
      m[ti][h] = fmaxf(fmaxf(s_redm[idx][0], s_redm[idx][1]),
                       fmaxf(s_redm[idx][2], s_redm[idx][3]));
    }

  // exp in registers, sum-reduce
  float inv[2][4];
  #pragma unroll
  for (int ti = 0; ti < 2; ++ti)
    #pragma unroll
    for (int h = 0; h < HEADS; ++h) {
      sc[ti][h].x = __expf(sc[ti][h].x - m[ti][h]);
      sc[ti][h].y = __expf(sc[ti][h].y - m[ti][h]);
      sc[ti][h].z = __expf(sc[ti][h].z - m[ti][h]);
      sc[ti][h].w = __expf(sc[ti][h].w - m[ti][h]);
      float s = sc[ti][h].x + sc[ti][h].y + sc[ti][h].z + sc[ti][h].w;
      for (int off = 32; off; off >>= 1) s += __shfl_xor(s, off);
      if (lane == 0) s_reds[ti * 4 + h][w] = s;
    }
  __syncthreads();
  #pragma unroll
  for (int ti = 0; ti < 2; ++ti)
    #pragma unroll
    for (int h = 0; h < HEADS; ++h) {
      const int idx = ti * 4 + h;
      inv[ti][h] = 0.25f / (s_reds[idx][0] + s_reds[idx][1] + s_reds[idx][2] + s_reds[idx][3]);
    }

  #pragma unroll
  for (int ti = 0; ti < 2; ++ti) {
    float4 o;
    o.x = sc[ti][0].x * inv[ti][0] + sc[ti][1].x * inv[ti][1] +
          sc[ti][2].x * inv[ti][2] + sc[ti][3].x * inv[ti][3];
    o.y = sc[ti][0].y * inv[ti][0] + sc[ti][1].y * inv[ti][1] +
          sc[ti][2].y * inv[ti][2] + sc[ti][3].y * inv[ti][3];
    o.z = sc[ti][0].z * inv[ti][0] + sc[ti][1].z * inv[ti][1] +
          sc[ti][2].z * inv[ti][2] + sc[ti][3].z * inv[ti][3];
    o.w = sc[ti][0].w * inv[ti][0] + sc[ti][1].w * inv[ti][1] +
          sc[ti][2].w * inv[ti][2] + sc[ti][3].w * inv[ti][3];
    ((float4*)(out0 + (i0 + ti) * N))[t] = o;
  }
}

// ---------------- Pairwise MLPs: edge features + edge probability ----------------
// One block per i; thread t owns j = 4t..4t+3 (float4 sb loads, 68 FMAs per load).
__global__ __launch_bounds__(256) void k_pair(
    const float* __restrict__ sa_p, const float* __restrict__ sb_pT,
    const float* __restrict__ pb1, const float* __restrict__ pw2, const float* __restrict__ pb2,
    const float* __restrict__ sa_c, const float* __restrict__ sb_cT,
    const float* __restrict__ cb1, const float* __restrict__ cw2, const float* __restrict__ cb2,
    float* __restrict__ out1, float* __restrict__ out2)
{
  __shared__ float s_ap[H];
  __shared__ float s_ac[64];
  const int i = blockIdx.x;
  const int t = threadIdx.x;
  if (t < H) s_ap[t] = sa_p[i * H + t] + pb1[t];
  else if (t < H + 64) s_ac[t - H] = sa_c[i * 64 + (t - H)] + cb1[t - H];
  __syncthreads();

  const float4* sbp4 = (const float4*)sb_pT;  // [128][256]
  const float4* sbc4 = (const float4*)sb_cT;  // [64][256]

  float4 acc[EF];
  #pragma unroll
  for (int e = 0; e < EF; ++e) {
    const float b = pb2[e];
    acc[e].x = b; acc[e].y = b; acc[e].z = b; acc[e].w = b;
  }
  #pragma unroll 2
  for (int k = 0; k < H; ++k) {
    const float a = s_ap[k];
    const float4 sb = sbp4[k * 256 + t];
    float4 hh;
    hh.x = fmaxf(a + sb.x, 0.f); hh.y = fmaxf(a + sb.y, 0.f);
    hh.z = fmaxf(a + sb.z, 0.f); hh.w = fmaxf(a + sb.w, 0.f);
    const float* wk = pw2 + k * EF;   // uniform -> scalar loads -> SGPR operands
    #pragma unroll
    for (int e = 0; e < EF; ++e) {
      const float we = wk[e];
      acc[e].x = fmaf(hh.x, we, acc[e].x); acc[e].y = fmaf(hh.y, we, acc[e].y);
      acc[e].z = fmaf(hh.z, we, acc[e].z); acc[e].w = fmaf(hh.w, we, acc[e].w);
    }
  }
  // stores: j-major, 17 contiguous floats per j
  float* o2 = out2 + ((size_t)i * N + 4 * (size_t)t) * EF;
  #pragma unroll
  for (int e = 0; e < EF; ++e) o2[0 * EF + e] = acc[e].x;
  #pragma unroll
  for (int e = 0; e < EF; ++e) o2[1 * EF + e] = acc[e].y;
  #pragma unroll
  for (int e = 0; e < EF; ++e) o2[2 * EF + e] = acc[e].z;
  #pragma unroll
  for (int e = 0; e < EF; ++e) o2[3 * EF + e] = acc[e].w;

  float4 ac = {0.f, 0.f, 0.f, 0.f};
  #pragma unroll 2
  for (int k = 0; k < 64; ++k) {
    const float a = s_ac[k];
    const float4 sb = sbc4[k * 256 + t];
    const float we = cw2[k];
    ac.x = fmaf(fmaxf(a + sb.x, 0.f), we, ac.x);
    ac.y = fmaf(fmaxf(a + sb.y, 0.f), we, ac.y);
    ac.z = fmaf(fmaxf(a + sb.z, 0.f), we, ac.z);
    ac.w = fmaf(fmaxf(a + sb.w, 0.f), we, ac.w);
  }
  const float cb = cb2[0];
  float4 o;
  o.x = 1.f / (1.f + __expf(-(ac.x + cb)));
  o.y = 1.f / (1.f + __expf(-(ac.y + cb)));
  o.z = 1.f / (1.f + __expf(-(ac.z + cb)));
  o.w = 1.f / (1.f + __expf(-(ac.w + cb)));
  ((float4*)(out1 + (size_t)i * N))[t] = o;
}

extern "C" void kernel_launch(void* const* d_in, const int* in_sizes, int n_in,
                              void* d_out, int out_size, void* d_ws, size_t ws_size,
                              hipStream_t stream) {
  const float* nf  = (const float*)d_in[0];
  const float* ew1 = (const float*)d_in[1];
  const float* eb1 = (const float*)d_in[2];
  const float* ew2 = (const float*)d_in[3];
  const float* eb2 = (const float*)d_in[4];
  const float* ipw = (const float*)d_in[5];
  const float* ipb = (const float*)d_in[6];
  const float* pw1 = (const float*)d_in[7];
  const float* pb1 = (const float*)d_in[8];
  const float* pw2 = (const float*)d_in[9];
  const float* pb2 = (const float*)d_in[10];
  const float* cw1 = (const float*)d_in[11];
  const float* cb1 = (const float*)d_in[12];
  const float* cw2 = (const float*)d_in[13];
  const float* cb2 = (const float*)d_in[14];

  float* ws = (float*)d_ws;
  float* enc   = ws;                 // 1024*128
  float* q     = ws + 131072;        // 1024*128
  float* kkT   = ws + 262144;        // 128*1024 (transposed)
  float* sa_p  = ws + 393216;        // 1024*128
  float* sb_pT = ws + 524288;        // 128*1024 (transposed)
  float* sa_c  = ws + 655360;        // 1024*64
  float* sb_cT = ws + 720896;        // 64*1024 (transposed)

  float* out0 = (float*)d_out;             // attention_weights [1024*1024]
  float* out1 = out0 + N * N;              // edge_probabilities [1024*1024]
  float* out2 = out0 + 2 * N * N;          // predicted_edge_features [1024*1024*17]

  k_encoder<<<N, 128, 0, stream>>>(nf, ew1, eb1, ew2, eb2, enc);
  k_proj<<<N, 256, 0, stream>>>(enc, ipw, ipb, pw1, cw1, q, kkT, sa_p, sb_pT, sa_c, sb_cT);
  k_attn<<<N / 2, 256, 0, stream>>>(q, kkT, out0);
  k_pair<<<N, 256, 0, stream>>>(sa_p, sb_pT, pb1, pw2, pb2,
                                sa_c, sb_cT, cb1, cw2, cb2, out1, out2);
}

// Round 5
// 106.671 us; speedup vs baseline: 2.1677x; 1.1809x over previous
//
#include <hip/hip_runtime.h>
#include <hip/hip_bf16.h>

// Problem constants
#define N 1024
#define NF 27
#define EF 17
#define H 128
#define HEADS 4
#define HD 32

typedef __attribute__((ext_vector_type(8))) short bf16x8;
typedef __attribute__((ext_vector_type(16))) float f32x16;

__device__ __forceinline__ short f2bf(float x) {
  return __builtin_bit_cast(short, __float2bfloat16(x));
}

// ---------------- Encoder: enc = relu(nf@w1+b1)@w2+b2 ----------------
__global__ __launch_bounds__(128) void k_encoder(
    const float* __restrict__ nf, const float* __restrict__ w1, const float* __restrict__ b1,
    const float* __restrict__ w2, const float* __restrict__ b2, float* __restrict__ enc)
{
  __shared__ float s_nf[NF];
  __shared__ float s_h1[H];
  const int i = blockIdx.x, t = threadIdx.x;
  if (t < NF) s_nf[t] = nf[i * NF + t];
  __syncthreads();
  float h = b1[t];
  #pragma unroll
  for (int f = 0; f < NF; ++f) h = fmaf(s_nf[f], w1[f * H + t], h);
  h = fmaxf(h, 0.f);
  s_h1[t] = h;
  __syncthreads();
  float acc = b2[t];
  #pragma unroll 8
  for (int k = 0; k < H; ++k) acc = fmaf(s_h1[k], w2[k * H + t], acc);
  enc[i * H + t] = acc;
}

// ---------------- Projections: q, kkT (transposed), sa_p, sb_p (ROW-major), sa_c, sb_c^T ----------------
__global__ __launch_bounds__(256) void k_proj(
    const float* __restrict__ enc,
    const float* __restrict__ ipw, const float* __restrict__ ipb,
    const float* __restrict__ pw1, const float* __restrict__ cw1,
    float* __restrict__ q, float* __restrict__ kkT,
    float* __restrict__ sa_p, float* __restrict__ sb_p,
    float* __restrict__ sa_c, float* __restrict__ sb_cT)
{
  __shared__ float s_e[H];
  const int i = blockIdx.x, t = threadIdx.x;
  if (t < H) s_e[t] = enc[i * H + t];
  __syncthreads();
  for (int c = t; c < 640; c += 256) {
    float acc;
    if (c < 256) {
      acc = ipb[c];
      const float* wcol = ipw + c;
      #pragma unroll 8
      for (int k = 0; k < H; ++k) acc = fmaf(s_e[k], wcol[k * 384], acc);
      if (c < 128) q[i * H + c] = acc;
      else         kkT[(c - 128) * N + i] = acc;   // transposed for coalesced attn reads
    } else if (c < 512) {
      const int cc = (c < 384) ? (c - 256) : (c - 384);
      const float* wcol = (c < 384) ? (pw1 + cc) : (pw1 + 128 * H + cc);
      acc = 0.f;
      #pragma unroll 8
      for (int k = 0; k < H; ++k) acc = fmaf(s_e[k], wcol[k * H], acc);
      if (c < 384) sa_p[i * H + cc] = acc;
      else         sb_p[i * H + cc] = acc;   // ROW-major: pair kernel A-fragment reads
    } else {
      const int cc = (c < 576) ? (c - 512) : (c - 576);
      const float* wcol = (c < 576) ? (cw1 + cc) : (cw1 + 128 * 64 + cc);
      acc = 0.f;
      #pragma unroll 8
      for (int k = 0; k < H; ++k) acc = fmaf(s_e[k], wcol[k * 64], acc);
      if (c < 576) sa_c[i * 64 + cc] = acc;
      else         sb_cT[cc * N + i] = acc;
    }
  }
}

// ---------------- Attention weights: softmax(QK^T/sqrt(hd)) mean over heads ----------------
__global__ __launch_bounds__(256) void k_attn(
    const float* __restrict__ q, const float* __restrict__ kkT, float* __restrict__ out0)
{
  __shared__ float s_q[2][H];
  __shared__ float s_redm[8][4];
  __shared__ float s_reds[8][4];
  const int i0 = blockIdx.x * 2, t = threadIdx.x;
  const int w = t >> 6, lane = t & 63;
  s_q[t >> 7][t & 127] = q[(i0 + (t >> 7)) * H + (t & 127)];
  __syncthreads();

  const float scale = 0.17677669529663687f;  // 1/sqrt(32)
  const float4* kT4 = (const float4*)kkT;    // [128][256] float4 rows
  float4 sc[2][4];

  #pragma unroll
  for (int h = 0; h < HEADS; ++h) {
    float4 a0 = {0.f, 0.f, 0.f, 0.f}, a1 = {0.f, 0.f, 0.f, 0.f};
    #pragma unroll 8
    for (int d = 0; d < HD; ++d) {
      const float4 kv = kT4[(h * HD + d) * 256 + t];
      const float q0 = s_q[0][h * HD + d], q1 = s_q[1][h * HD + d];
      a0.x = fmaf(q0, kv.x, a0.x); a0.y = fmaf(q0, kv.y, a0.y);
      a0.z = fmaf(q0, kv.z, a0.z); a0.w = fmaf(q0, kv.w, a0.w);
      a1.x = fmaf(q1, kv.x, a1.x); a1.y = fmaf(q1, kv.y, a1.y);
      a1.z = fmaf(q1, kv.z, a1.z); a1.w = fmaf(q1, kv.w, a1.w);
    }
    sc[0][h].x = a0.x * scale; sc[0][h].y = a0.y * scale;
    sc[0][h].z = a0.z * scale; sc[0][h].w = a0.w * scale;
    sc[1][h].x = a1.x * scale; sc[1][h].y = a1.y * scale;
    sc[1][h].z = a1.z * scale; sc[1][h].w = a1.w * scale;
  }

  float m[2][4];
  #pragma unroll
  for (int ti = 0; ti < 2; ++ti)
    #pragma unroll
    for (int h = 0; h < HEADS; ++h) {
      float mm = fmaxf(fmaxf(sc[ti][h].x, sc[ti][h].y), fmaxf(sc[ti][h].z, sc[ti][h].w));
      for (int off = 32; off; off >>= 1) mm = fmaxf(mm, __shfl_xor(mm, off));
      if (lane == 0) s_redm[ti * 4 + h][w] = mm;
    }
  __syncthreads();
  #pragma unroll
  for (int ti = 0; ti < 2; ++ti)
    #pragma unroll
    for (int h = 0; h < HEADS; ++h) {
      const int idx = ti * 4 + h;
      m[ti][h] = fmaxf(fmaxf(s_redm[idx][0], s_redm[idx][1]),
                       fmaxf(s_redm[idx][2], s_redm[idx][3]));
    }

  float inv[2][4];
  #pragma unroll
  for (int ti = 0; ti < 2; ++ti)
    #pragma unroll
    for (int h = 0; h < HEADS; ++h) {
      sc[ti][h].x = __expf(sc[ti][h].x - m[ti][h]);
      sc[ti][h].y = __expf(sc[ti][h].y - m[ti][h]);
      sc[ti][h].z = __expf(sc[ti][h].z - m[ti][h]);
      sc[ti][h].w = __expf(sc[ti][h].w - m[ti][h]);
      float s = sc[ti][h].x + sc[ti][h].y + sc[ti][h].z + sc[ti][h].w;
      for (int off = 32; off; off >>= 1) s += __shfl_xor(s, off);
      if (lane == 0) s_reds[ti * 4 + h][w] = s;
    }
  __syncthreads();
  #pragma unroll
  for (int ti = 0; ti < 2; ++ti)
    #pragma unroll
    for (int h = 0; h < HEADS; ++h) {
      const int idx = ti * 4 + h;
      inv[ti][h] = 0.25f / (s_reds[idx][0] + s_reds[idx][1] + s_reds[idx][2] + s_reds[idx][3]);
    }

  #pragma unroll
  for (int ti = 0; ti < 2; ++ti) {
    float4 o;
    o.x = sc[ti][0].x * inv[ti][0] + sc[ti][1].x * inv[ti][1] +
          sc[ti][2].x * inv[ti][2] + sc[ti][3].x * inv[ti][3];
    o.y = sc[ti][0].y * inv[ti][0] + sc[ti][1].y * inv[ti][1] +
          sc[ti][2].y * inv[ti][2] + sc[ti][3].y * inv[ti][3];
    o.z = sc[ti][0].z * inv[ti][0] + sc[ti][1].z * inv[ti][1] +
          sc[ti][2].z * inv[ti][2] + sc[ti][3].z * inv[ti][3];
    o.w = sc[ti][0].w * inv[ti][0] + sc[ti][1].w * inv[ti][1] +
          sc[ti][2].w * inv[ti][2] + sc[ti][3].w * inv[ti][3];
    ((float4*)(out0 + (i0 + ti) * N))[t] = o;
  }
}

// ---------------- Pairwise MLPs via MFMA ----------------
// Block: 2 i's x 256 j's. 4 waves; wave handles 64 j (two 32x32 MFMA tiles).
__global__ __launch_bounds__(256) void k_pair(
    const float* __restrict__ sa_p, const float* __restrict__ sb_p,
    const float* __restrict__ pb1, const float* __restrict__ pw2, const float* __restrict__ pb2,
    const float* __restrict__ sa_c, const float* __restrict__ sb_cT,
    const float* __restrict__ cb1, const float* __restrict__ cw2, const float* __restrict__ cb2,
    float* __restrict__ out1, float* __restrict__ out2)
{
  __shared__ float s_ap[2][H];
  __shared__ float s_ac[2][64];
  __shared__ float s_w2[H * EF];
  __shared__ float s_out[2][256 * EF];   // 2 x 17408 B

  const int t = threadIdx.x;
  const int lane = t & 63, wid = t >> 6;
  const int bid = blockIdx.x;
  const int ip = bid >> 2, jb = bid & 3;
  const int i0 = ip * 2;

  for (int c = t; c < H * EF; c += 256) s_w2[c] = pw2[c];
  // ALL threads stage s_ap (2*128 = 256 entries); threads 0..127 ALSO stage s_ac.
  s_ap[t >> 7][t & 127] = sa_p[(i0 + (t >> 7)) * H + (t & 127)] + pb1[t & 127];
  if (t < 128)
    s_ac[t >> 6][t & 63] = sa_c[(i0 + (t >> 6)) * 64 + (t & 63)] + cb1[t & 63];
  __syncthreads();

  const int col = lane & 31;     // MFMA N-col (feature), B col / C col
  const int hsel = lane >> 5;    // half-select: k-subgroup
  // B fragments: lane holds B[k = kc*16 + hsel*8 + e][col]
  bf16x8 bfrag[8];
  #pragma unroll
  for (int kc = 0; kc < 8; ++kc) {
    #pragma unroll
    for (int e = 0; e < 8; ++e) {
      const int k = kc * 16 + hsel * 8 + e;
      bfrag[kc][e] = f2bf((col < EF) ? s_w2[k * EF + col] : 0.f);
    }
  }
  const float pb2c = (col < EF) ? pb2[col] : 0.f;

  #pragma unroll
  for (int tt = 0; tt < 2; ++tt) {
    const int jloc = wid * 64 + tt * 32 + (lane & 31);      // j within block tile (0..255)
    const int j = jb * 256 + jloc;
    const float4* sbrow = (const float4*)(sb_p + j * H);    // lane's own A-row
    f32x16 acc0, acc1;
    #pragma unroll
    for (int r = 0; r < 16; ++r) { acc0[r] = 0.f; acc1[r] = 0.f; }

    #pragma unroll
    for (int kc = 0; kc < 8; ++kc) {
      const float4 v0 = sbrow[kc * 4 + hsel * 2 + 0];
      const float4 v1 = sbrow[kc * 4 + hsel * 2 + 1];
      const float4 c00 = *(const float4*)&s_ap[0][kc * 16 + hsel * 8];
      const float4 c01 = *(const float4*)&s_ap[0][kc * 16 + hsel * 8 + 4];
      const float4 c10 = *(const float4*)&s_ap[1][kc * 16 + hsel * 8];
      const float4 c11 = *(const float4*)&s_ap[1][kc * 16 + hsel * 8 + 4];
      bf16x8 a;
      a[0] = f2bf(fmaxf(c00.x + v0.x, 0.f));
      a[1] = f2bf(fmaxf(c00.y + v0.y, 0.f));
      a[2] = f2bf(fmaxf(c00.z + v0.z, 0.f));
      a[3] = f2bf(fmaxf(c00.w + v0.w, 0.f));
      a[4] = f2bf(fmaxf(c01.x + v1.x, 0.f));
      a[5] = f2bf(fmaxf(c01.y + v1.y, 0.f));
      a[6] = f2bf(fmaxf(c01.z + v1.z, 0.f));
      a[7] = f2bf(fmaxf(c01.w + v1.w, 0.f));
      acc0 = __builtin_amdgcn_mfma_f32_32x32x16_bf16(a, bfrag[kc], acc0, 0, 0, 0);
      a[0] = f2bf(fmaxf(c10.x + v0.x, 0.f));
      a[1] = f2bf(fmaxf(c10.y + v0.y, 0.f));
      a[2] = f2bf(fmaxf(c10.z + v0.z, 0.f));
      a[3] = f2bf(fmaxf(c10.w + v0.w, 0.f));
      a[4] = f2bf(fmaxf(c11.x + v1.x, 0.f));
      a[5] = f2bf(fmaxf(c11.y + v1.y, 0.f));
      a[6] = f2bf(fmaxf(c11.z + v1.z, 0.f));
      a[7] = f2bf(fmaxf(c11.w + v1.w, 0.f));
      acc1 = __builtin_amdgcn_mfma_f32_32x32x16_bf16(a, bfrag[kc], acc1, 0, 0, 0);
    }

    if (col < EF) {
      const int rbase = wid * 64 + tt * 32 + 4 * hsel;
      #pragma unroll
      for (int r = 0; r < 16; ++r) {
        const int row = rbase + (r & 3) + 8 * (r >> 2);
        s_out[0][row * EF + col] = acc0[r] + pb2c;
        s_out[1][row * EF + col] = acc1[r] + pb2c;
      }
    }
  }

  // classifier path (VALU): thread t owns exactly j = jb*256 + t, both i's
  {
    const int j = jb * 256 + t;
    float ac0 = 0.f, ac1 = 0.f;
    #pragma unroll 4
    for (int k = 0; k < 64; ++k) {
      const float sb = sb_cT[k * N + j];
      const float a0 = s_ac[0][k], a1 = s_ac[1][k];
      const float we = cw2[k];
      ac0 = fmaf(fmaxf(a0 + sb, 0.f), we, ac0);
      ac1 = fmaf(fmaxf(a1 + sb, 0.f), we, ac1);
    }
    const float cb = cb2[0];
    out1[(size_t)i0 * N + j]       = 1.f / (1.f + __expf(-(ac0 + cb)));
    out1[(size_t)(i0 + 1) * N + j] = 1.f / (1.f + __expf(-(ac1 + cb)));
  }

  __syncthreads();
  // coalesced out2 write: 256 j x 17 feats per i = 1088 float4 each
  #pragma unroll
  for (int i = 0; i < 2; ++i) {
    const float4* src = (const float4*)s_out[i];
    float4* dst = (float4*)(out2 + ((size_t)(i0 + i) * N + jb * 256) * EF);
    for (int c = t; c < 1088; c += 256) dst[c] = src[c];
  }
}

extern "C" void kernel_launch(void* const* d_in, const int* in_sizes, int n_in,
                              void* d_out, int out_size, void* d_ws, size_t ws_size,
                              hipStream_t stream) {
  const float* nf  = (const float*)d_in[0];
  const float* ew1 = (const float*)d_in[1];
  const float* eb1 = (const float*)d_in[2];
  const float* ew2 = (const float*)d_in[3];
  const float* eb2 = (const float*)d_in[4];
  const float* ipw = (const float*)d_in[5];
  const float* ipb = (const float*)d_in[6];
  const float* pw1 = (const float*)d_in[7];
  const float* pb1 = (const float*)d_in[8];
  const float* pw2 = (const float*)d_in[9];
  const float* pb2 = (const float*)d_in[10];
  const float* cw1 = (const float*)d_in[11];
  const float* cb1 = (const float*)d_in[12];
  const float* cw2 = (const float*)d_in[13];
  const float* cb2 = (const float*)d_in[14];

  float* ws = (float*)d_ws;
  float* enc   = ws;                 // 1024*128
  float* q     = ws + 131072;        // 1024*128
  float* kkT   = ws + 262144;        // 128*1024 (transposed)
  float* sa_p  = ws + 393216;        // 1024*128
  float* sb_p  = ws + 524288;        // 1024*128 (ROW-major)
  float* sa_c  = ws + 655360;        // 1024*64
  float* sb_cT = ws + 720896;        // 64*1024 (transposed)

  float* out0 = (float*)d_out;             // attention_weights [1024*1024]
  float* out1 = out0 + N * N;              // edge_probabilities [1024*1024]
  float* out2 = out0 + 2 * N * N;          // predicted_edge_features [1024*1024*17]

  k_encoder<<<N, 128, 0, stream>>>(nf, ew1, eb1, ew2, eb2, enc);
  k_proj<<<N, 256, 0, stream>>>(enc, ipw, ipb, pw1, cw1, q, kkT, sa_p, sb_p, sa_c, sb_cT);
  k_attn<<<N / 2, 256, 0, stream>>>(q, kkT, out0);
  k_pair<<<512 * 4, 256, 0, stream>>>(sa_p, sb_p, pb1, pw2, pb2,
                                      sa_c, sb_cT, cb1, cw2, cb2, out1, out2);
}

// Round 6
// 102.059 us; speedup vs baseline: 2.2657x; 1.0452x over previous
//
#include <hip/hip_runtime.h>
#include <hip/hip_bf16.h>

// Problem constants
#define N 1024
#define NF 27
#define EF 17
#define H 128
#define HEADS 4
#define HD 32

typedef __attribute__((ext_vector_type(8))) short bf16x8;
typedef __attribute__((ext_vector_type(16))) float f32x16;

__device__ __forceinline__ short f2bf(float x) {
  return __builtin_bit_cast(short, __float2bfloat16(x));
}

// ---------------- Encoder: enc = relu(nf@w1+b1)@w2+b2 ----------------
__global__ __launch_bounds__(128) void k_encoder(
    const float* __restrict__ nf, const float* __restrict__ w1, const float* __restrict__ b1,
    const float* __restrict__ w2, const float* __restrict__ b2, float* __restrict__ enc)
{
  __shared__ float s_nf[NF];
  __shared__ float s_h1[H];
  const int i = blockIdx.x, t = threadIdx.x;
  if (t < NF) s_nf[t] = nf[i * NF + t];
  __syncthreads();
  float h = b1[t];
  #pragma unroll
  for (int f = 0; f < NF; ++f) h = fmaf(s_nf[f], w1[f * H + t], h);
  h = fmaxf(h, 0.f);
  s_h1[t] = h;
  __syncthreads();
  float acc = b2[t];
  #pragma unroll 8
  for (int k = 0; k < H; ++k) acc = fmaf(s_h1[k], w2[k * H + t], acc);
  enc[i * H + t] = acc;
}

// ---------------- Projections ----------------
// sb_p is written SWIZZLED into MFMA A-fragment order:
//   float4 chunk CH = J*32 + kc*4 + hsel*2 + half   (J = j>>5)
//   sb_ps4[CH*32 + (j&31)] = sb_p[j][kc*16 + hsel*8 + half*4 .. +3]
// so k_pair's A-loads are instruction-contiguous (lanes 0..31 -> 512B segment).
__global__ __launch_bounds__(256) void k_proj(
    const float* __restrict__ enc,
    const float* __restrict__ ipw, const float* __restrict__ ipb,
    const float* __restrict__ pw1, const float* __restrict__ cw1,
    float* __restrict__ q, float* __restrict__ kkT,
    float* __restrict__ sa_p, float* __restrict__ sb_ps,
    float* __restrict__ sa_c, float* __restrict__ sb_cT)
{
  __shared__ float s_e[H];
  const int i = blockIdx.x, t = threadIdx.x;
  if (t < H) s_e[t] = enc[i * H + t];
  __syncthreads();
  for (int c = t; c < 640; c += 256) {
    float acc;
    if (c < 256) {
      acc = ipb[c];
      const float* wcol = ipw + c;
      #pragma unroll 8
      for (int k = 0; k < H; ++k) acc = fmaf(s_e[k], wcol[k * 384], acc);
      if (c < 128) q[i * H + c] = acc;
      else         kkT[(c - 128) * N + i] = acc;   // transposed for coalesced attn reads
    } else if (c < 512) {
      const int cc = (c < 384) ? (c - 256) : (c - 384);
      const float* wcol = (c < 384) ? (pw1 + cc) : (pw1 + 128 * H + cc);
      acc = 0.f;
      #pragma unroll 8
      for (int k = 0; k < H; ++k) acc = fmaf(s_e[k], wcol[k * H], acc);
      if (c < 384) sa_p[i * H + cc] = acc;
      else {
        const int J = i >> 5, jl = i & 31;
        const int kc = cc >> 4, hs = (cc >> 3) & 1, hf = (cc >> 2) & 1, pos = cc & 3;
        sb_ps[(((J * 32 + kc * 4 + hs * 2 + hf) * 32) + jl) * 4 + pos] = acc;
      }
    } else {
      const int cc = (c < 576) ? (c - 512) : (c - 576);
      const float* wcol = (c < 576) ? (cw1 + cc) : (cw1 + 128 * 64 + cc);
      acc = 0.f;
      #pragma unroll 8
      for (int k = 0; k < H; ++k) acc = fmaf(s_e[k], wcol[k * 64], acc);
      if (c < 576) sa_c[i * 64 + cc] = acc;
      else         sb_cT[cc * N + i] = acc;
    }
  }
}

// ---------------- Attention weights: softmax(QK^T/sqrt(hd)) mean over heads ----------------
__global__ __launch_bounds__(256) void k_attn(
    const float* __restrict__ q, const float* __restrict__ kkT, float* __restrict__ out0)
{
  __shared__ float s_q[2][H];
  __shared__ float s_redm[8][4];
  __shared__ float s_reds[8][4];
  const int i0 = blockIdx.x * 2, t = threadIdx.x;
  const int w = t >> 6, lane = t & 63;
  s_q[t >> 7][t & 127] = q[(i0 + (t >> 7)) * H + (t & 127)];
  __syncthreads();

  const float scale = 0.17677669529663687f;  // 1/sqrt(32)
  const float4* kT4 = (const float4*)kkT;    // [128][256] float4 rows
  float4 sc[2][4];

  #pragma unroll
  for (int h = 0; h < HEADS; ++h) {
    float4 a0 = {0.f, 0.f, 0.f, 0.f}, a1 = {0.f, 0.f, 0.f, 0.f};
    #pragma unroll 8
    for (int d = 0; d < HD; ++d) {
      const float4 kv = kT4[(h * HD + d) * 256 + t];
      const float q0 = s_q[0][h * HD + d], q1 = s_q[1][h * HD + d];
      a0.x = fmaf(q0, kv.x, a0.x); a0.y = fmaf(q0, kv.y, a0.y);
      a0.z = fmaf(q0, kv.z, a0.z); a0.w = fmaf(q0, kv.w, a0.w);
      a1.x = fmaf(q1, kv.x, a1.x); a1.y = fmaf(q1, kv.y, a1.y);
      a1.z = fmaf(q1, kv.z, a1.z); a1.w = fmaf(q1, kv.w, a1.w);
    }
    sc[0][h].x = a0.x * scale; sc[0][h].y = a0.y * scale;
    sc[0][h].z = a0.z * scale; sc[0][h].w = a0.w * scale;
    sc[1][h].x = a1.x * scale; sc[1][h].y = a1.y * scale;
    sc[1][h].z = a1.z * scale; sc[1][h].w = a1.w * scale;
  }

  float m[2][4];
  #pragma unroll
  for (int ti = 0; ti < 2; ++ti)
    #pragma unroll
    for (int h = 0; h < HEADS; ++h) {
      float mm = fmaxf(fmaxf(sc[ti][h].x, sc[ti][h].y), fmaxf(sc[ti][h].z, sc[ti][h].w));
      for (int off = 32; off; off >>= 1) mm = fmaxf(mm, __shfl_xor(mm, off));
      if (lane == 0) s_redm[ti * 4 + h][w] = mm;
    }
  __syncthreads();
  #pragma unroll
  for (int ti = 0; ti < 2; ++ti)
    #pragma unroll
    for (int h = 0; h < HEADS; ++h) {
      const int idx = ti * 4 + h;
      m[ti][h] = fmaxf(fmaxf(s_redm[idx][0], s_redm[idx][1]),
                       fmaxf(s_redm[idx][2], s_redm[idx][3]));
    }

  float inv[2][4];
  #pragma unroll
  for (int ti = 0; ti < 2; ++ti)
    #pragma unroll
    for (int h = 0; h < HEADS; ++h) {
      sc[ti][h].x = __expf(sc[ti][h].x - m[ti][h]);
      sc[ti][h].y = __expf(sc[ti][h].y - m[ti][h]);
      sc[ti][h].z = __expf(sc[ti][h].z - m[ti][h]);
      sc[ti][h].w = __expf(sc[ti][h].w - m[ti][h]);
      float s = sc[ti][h].x + sc[ti][h].y + sc[ti][h].z + sc[ti][h].w;
      for (int off = 32; off; off >>= 1) s += __shfl_xor(s, off);
      if (lane == 0) s_reds[ti * 4 + h][w] = s;
    }
  __syncthreads();
  #pragma unroll
  for (int ti = 0; ti < 2; ++ti)
    #pragma unroll
    for (int h = 0; h < HEADS; ++h) {
      const int idx = ti * 4 + h;
      inv[ti][h] = 0.25f / (s_reds[idx][0] + s_reds[idx][1] + s_reds[idx][2] + s_reds[idx][3]);
    }

  #pragma unroll
  for (int ti = 0; ti < 2; ++ti) {
    float4 o;
    o.x = sc[ti][0].x * inv[ti][0] + sc[ti][1].x * inv[ti][1] +
          sc[ti][2].x * inv[ti][2] + sc[ti][3].x * inv[ti][3];
    o.y = sc[ti][0].y * inv[ti][0] + sc[ti][1].y * inv[ti][1] +
          sc[ti][2].y * inv[ti][2] + sc[ti][3].y * inv[ti][3];
    o.z = sc[ti][0].z * inv[ti][0] + sc[ti][1].z * inv[ti][1] +
          sc[ti][2].z * inv[ti][2] + sc[ti][3].z * inv[ti][3];
    o.w = sc[ti][0].w * inv[ti][0] + sc[ti][1].w * inv[ti][1] +
          sc[ti][2].w * inv[ti][2] + sc[ti][3].w * inv[ti][3];
    ((float4*)(out0 + (i0 + ti) * N))[t] = o;
  }
}

// ---------------- Pairwise MLPs via MFMA ----------------
// Block: 2 i's x 256 j's. 4 waves; wave handles 64 j (two 32x32 MFMA tiles).
// sb_ps is pre-swizzled so each A-load instruction reads contiguous 512B segments.
__global__ __launch_bounds__(256) void k_pair(
    const float* __restrict__ sa_p, const float* __restrict__ sb_ps,
    const float* __restrict__ pb1, const float* __restrict__ pw2, const float* __restrict__ pb2,
    const float* __restrict__ sa_c, const float* __restrict__ sb_cT,
    const float* __restrict__ cb1, const float* __restrict__ cw2, const float* __restrict__ cb2,
    float* __restrict__ out1, float* __restrict__ out2)
{
  __shared__ float s_ap[2][H];
  __shared__ float s_ac[2][64];
  __shared__ float s_out[2][256 * EF];   // 2 x 17408 B

  const int t = threadIdx.x;
  const int lane = t & 63, wid = t >> 6;
  const int bid = blockIdx.x;
  const int ip = bid >> 2, jb = bid & 3;
  const int i0 = ip * 2;

  // ALL threads stage s_ap (2*128 = 256 entries); threads 0..127 ALSO stage s_ac.
  s_ap[t >> 7][t & 127] = sa_p[(i0 + (t >> 7)) * H + (t & 127)] + pb1[t & 127];
  if (t < 128)
    s_ac[t >> 6][t & 63] = sa_c[(i0 + (t >> 6)) * 64 + (t & 63)] + cb1[t & 63];
  __syncthreads();

  const int col = lane & 31;     // MFMA N-col (feature), B col / C col
  const int hsel = lane >> 5;    // half-select: k-subgroup
  // B fragments straight from global (L2-hot, 8.7KB): lane holds B[k=kc*16+hsel*8+e][col]
  bf16x8 bfrag[8];
  #pragma unroll
  for (int kc = 0; kc < 8; ++kc) {
    #pragma unroll
    for (int e = 0; e < 8; ++e) {
      const int k = kc * 16 + hsel * 8 + e;
      bfrag[kc][e] = f2bf((col < EF) ? pw2[k * EF + col] : 0.f);
    }
  }
  const float pb2c = (col < EF) ? pb2[col] : 0.f;

  const float4* sb4 = (const float4*)sb_ps;

  #pragma unroll
  for (int tt = 0; tt < 2; ++tt) {
    const int Jg = jb * 8 + wid * 2 + tt;   // global 32-j tile index
    f32x16 acc0, acc1;
    #pragma unroll
    for (int r = 0; r < 16; ++r) { acc0[r] = 0.f; acc1[r] = 0.f; }

    #pragma unroll
    for (int kc = 0; kc < 8; ++kc) {
      const int cb = (Jg * 32 + kc * 4 + hsel * 2) * 32 + col;
      const float4 v0 = sb4[cb];        // half 0: k = kc*16+hsel*8 .. +3
      const float4 v1 = sb4[cb + 32];   // half 1: k = kc*16+hsel*8+4 .. +7
      const float4 c00 = *(const float4*)&s_ap[0][kc * 16 + hsel * 8];
      const float4 c01 = *(const float4*)&s_ap[0][kc * 16 + hsel * 8 + 4];
      const float4 c10 = *(const float4*)&s_ap[1][kc * 16 + hsel * 8];
      const float4 c11 = *(const float4*)&s_ap[1][kc * 16 + hsel * 8 + 4];
      bf16x8 a;
      a[0] = f2bf(fmaxf(c00.x + v0.x, 0.f));
      a[1] = f2bf(fmaxf(c00.y + v0.y, 0.f));
      a[2] = f2bf(fmaxf(c00.z + v0.z, 0.f));
      a[3] = f2bf(fmaxf(c00.w + v0.w, 0.f));
      a[4] = f2bf(fmaxf(c01.x + v1.x, 0.f));
      a[5] = f2bf(fmaxf(c01.y + v1.y, 0.f));
      a[6] = f2bf(fmaxf(c01.z + v1.z, 0.f));
      a[7] = f2bf(fmaxf(c01.w + v1.w, 0.f));
      acc0 = __builtin_amdgcn_mfma_f32_32x32x16_bf16(a, bfrag[kc], acc0, 0, 0, 0);
      a[0] = f2bf(fmaxf(c10.x + v0.x, 0.f));
      a[1] = f2bf(fmaxf(c10.y + v0.y, 0.f));
      a[2] = f2bf(fmaxf(c10.z + v0.z, 0.f));
      a[3] = f2bf(fmaxf(c10.w + v0.w, 0.f));
      a[4] = f2bf(fmaxf(c11.x + v1.x, 0.f));
      a[5] = f2bf(fmaxf(c11.y + v1.y, 0.f));
      a[6] = f2bf(fmaxf(c11.z + v1.z, 0.f));
      a[7] = f2bf(fmaxf(c11.w + v1.w, 0.f));
      acc1 = __builtin_amdgcn_mfma_f32_32x32x16_bf16(a, bfrag[kc], acc1, 0, 0, 0);
    }

    if (col < EF) {
      const int rbase = wid * 64 + tt * 32 + 4 * hsel;
      #pragma unroll
      for (int r = 0; r < 16; ++r) {
        const int row = rbase + (r & 3) + 8 * (r >> 2);
        s_out[0][row * EF + col] = acc0[r] + pb2c;
        s_out[1][row * EF + col] = acc1[r] + pb2c;
      }
    }
  }

  // classifier path (VALU): thread t owns exactly j = jb*256 + t, both i's
  {
    const int j = jb * 256 + t;
    float ac0 = 0.f, ac1 = 0.f;
    #pragma unroll 4
    for (int k = 0; k < 64; ++k) {
      const float sb = sb_cT[k * N + j];
      const float a0 = s_ac[0][k], a1 = s_ac[1][k];
      const float we = cw2[k];
      ac0 = fmaf(fmaxf(a0 + sb, 0.f), we, ac0);
      ac1 = fmaf(fmaxf(a1 + sb, 0.f), we, ac1);
    }
    const float cb = cb2[0];
    out1[(size_t)i0 * N + j]       = 1.f / (1.f + __expf(-(ac0 + cb)));
    out1[(size_t)(i0 + 1) * N + j] = 1.f / (1.f + __expf(-(ac1 + cb)));
  }

  __syncthreads();
  // coalesced out2 write: 256 j x 17 feats per i = 1088 float4 each
  #pragma unroll
  for (int i = 0; i < 2; ++i) {
    const float4* src = (const float4*)s_out[i];
    float4* dst = (float4*)(out2 + ((size_t)(i0 + i) * N + jb * 256) * EF);
    for (int c = t; c < 1088; c += 256) dst[c] = src[c];
  }
}

extern "C" void kernel_launch(void* const* d_in, const int* in_sizes, int n_in,
                              void* d_out, int out_size, void* d_ws, size_t ws_size,
                              hipStream_t stream) {
  const float* nf  = (const float*)d_in[0];
  const float* ew1 = (const float*)d_in[1];
  const float* eb1 = (const float*)d_in[2];
  const float* ew2 = (const float*)d_in[3];
  const float* eb2 = (const float*)d_in[4];
  const float* ipw = (const float*)d_in[5];
  const float* ipb = (const float*)d_in[6];
  const float* pw1 = (const float*)d_in[7];
  const float* pb1 = (const float*)d_in[8];
  const float* pw2 = (const float*)d_in[9];
  const float* pb2 = (const float*)d_in[10];
  const float* cw1 = (const float*)d_in[11];
  const float* cb1 = (const float*)d_in[12];
  const float* cw2 = (const float*)d_in[13];
  const float* cb2 = (const float*)d_in[14];

  float* ws = (float*)d_ws;
  float* enc   = ws;                 // 1024*128
  float* q     = ws + 131072;        // 1024*128
  float* kkT   = ws + 262144;        // 128*1024 (transposed)
  float* sa_p  = ws + 393216;        // 1024*128
  float* sb_ps = ws + 524288;        // 1024*128 (MFMA-swizzled)
  float* sa_c  = ws + 655360;        // 1024*64
  float* sb_cT = ws + 720896;        // 64*1024 (transposed)

  float* out0 = (float*)d_out;             // attention_weights [1024*1024]
  float* out1 = out0 + N * N;              // edge_probabilities [1024*1024]
  float* out2 = out0 + 2 * N * N;          // predicted_edge_features [1024*1024*17]

  k_encoder<<<N, 128, 0, stream>>>(nf, ew1, eb1, ew2, eb2, enc);
  k_proj<<<N, 256, 0, stream>>>(enc, ipw, ipb, pw1, cw1, q, kkT, sa_p, sb_ps, sa_c, sb_cT);
  k_attn<<<N / 2, 256, 0, stream>>>(q, kkT, out0);
  k_pair<<<512 * 4, 256, 0, stream>>>(sa_p, sb_ps, pb1, pw2, pb2,
                                      sa_c, sb_cT, cb1, cw2, cb2, out1, out2);
}

// Round 7
// 100.643 us; speedup vs baseline: 2.2976x; 1.0141x over previous
//
#include <hip/hip_runtime.h>
#include <hip/hip_bf16.h>

// Problem constants
#define N 1024
#define NF 27
#define EF 17
#define H 128
#define HEADS 4
#define HD 32

typedef __attribute__((ext_vector_type(8))) short bf16x8;
typedef __attribute__((ext_vector_type(16))) float f32x16;

__device__ __forceinline__ short f2bf(float x) {
  return __builtin_bit_cast(short, __float2bfloat16(x));
}

// ---------------- Encoder: enc = relu(nf@w1+b1)@w2+b2 ----------------
__global__ __launch_bounds__(128) void k_encoder(
    const float* __restrict__ nf, const float* __restrict__ w1, const float* __restrict__ b1,
    const float* __restrict__ w2, const float* __restrict__ b2, float* __restrict__ enc)
{
  __shared__ float s_nf[NF];
  __shared__ float s_h1[H];
  const int i = blockIdx.x, t = threadIdx.x;
  if (t < NF) s_nf[t] = nf[i * NF + t];
  __syncthreads();
  float h = b1[t];
  #pragma unroll
  for (int f = 0; f < NF; ++f) h = fmaf(s_nf[f], w1[f * H + t], h);
  h = fmaxf(h, 0.f);
  s_h1[t] = h;
  __syncthreads();
  float acc = b2[t];
  #pragma unroll 8
  for (int k = 0; k < H; ++k) acc = fmaf(s_h1[k], w2[k * H + t], acc);
  enc[i * H + t] = acc;
}

// ---------------- Projections ----------------
// sb_p is written SWIZZLED into MFMA A-fragment order:
//   float4 chunk CH = J*32 + kc*4 + hsel*2 + half   (J = j>>5)
//   sb_ps4[CH*32 + (j&31)] = sb_p[j][kc*16 + hsel*8 + half*4 .. +3]
__global__ __launch_bounds__(256) void k_proj(
    const float* __restrict__ enc,
    const float* __restrict__ ipw, const float* __restrict__ ipb,
    const float* __restrict__ pw1, const float* __restrict__ cw1,
    float* __restrict__ q, float* __restrict__ kkT,
    float* __restrict__ sa_p, float* __restrict__ sb_ps,
    float* __restrict__ sa_c, float* __restrict__ sb_cT)
{
  __shared__ float s_e[H];
  const int i = blockIdx.x, t = threadIdx.x;
  if (t < H) s_e[t] = enc[i * H + t];
  __syncthreads();
  for (int c = t; c < 640; c += 256) {
    float acc;
    if (c < 256) {
      acc = ipb[c];
      const float* wcol = ipw + c;
      #pragma unroll 8
      for (int k = 0; k < H; ++k) acc = fmaf(s_e[k], wcol[k * 384], acc);
      if (c < 128) q[i * H + c] = acc;
      else         kkT[(c - 128) * N + i] = acc;   // transposed for coalesced attn reads
    } else if (c < 512) {
      const int cc = (c < 384) ? (c - 256) : (c - 384);
      const float* wcol = (c < 384) ? (pw1 + cc) : (pw1 + 128 * H + cc);
      acc = 0.f;
      #pragma unroll 8
      for (int k = 0; k < H; ++k) acc = fmaf(s_e[k], wcol[k * H], acc);
      if (c < 384) sa_p[i * H + cc] = acc;
      else {
        const int J = i >> 5, jl = i & 31;
        const int kc = cc >> 4, hs = (cc >> 3) & 1, hf = (cc >> 2) & 1, pos = cc & 3;
        sb_ps[(((J * 32 + kc * 4 + hs * 2 + hf) * 32) + jl) * 4 + pos] = acc;
      }
    } else {
      const int cc = (c < 576) ? (c - 512) : (c - 576);
      const float* wcol = (c < 576) ? (cw1 + cc) : (cw1 + 128 * 64 + cc);
      acc = 0.f;
      #pragma unroll 8
      for (int k = 0; k < H; ++k) acc = fmaf(s_e[k], wcol[k * 64], acc);
      if (c < 576) sa_c[i * 64 + cc] = acc;
      else         sb_cT[cc * N + i] = acc;
    }
  }
}

// ---------------- Attention weights: softmax(QK^T/sqrt(hd)) mean over heads ----------------
__global__ __launch_bounds__(256) void k_attn(
    const float* __restrict__ q, const float* __restrict__ kkT, float* __restrict__ out0)
{
  __shared__ float s_q[2][H];
  __shared__ float s_redm[8][4];
  __shared__ float s_reds[8][4];
  const int i0 = blockIdx.x * 2, t = threadIdx.x;
  const int w = t >> 6, lane = t & 63;
  s_q[t >> 7][t & 127] = q[(i0 + (t >> 7)) * H + (t & 127)];
  __syncthreads();

  const float scale = 0.17677669529663687f;  // 1/sqrt(32)
  const float4* kT4 = (const float4*)kkT;    // [128][256] float4 rows
  float4 sc[2][4];

  #pragma unroll
  for (int h = 0; h < HEADS; ++h) {
    float4 a0 = {0.f, 0.f, 0.f, 0.f}, a1 = {0.f, 0.f, 0.f, 0.f};
    #pragma unroll 8
    for (int d = 0; d < HD; ++d) {
      const float4 kv = kT4[(h * HD + d) * 256 + t];
      const float q0 = s_q[0][h * HD + d], q1 = s_q[1][h * HD + d];
      a0.x = fmaf(q0, kv.x, a0.x); a0.y = fmaf(q0, kv.y, a0.y);
      a0.z = fmaf(q0, kv.z, a0.z); a0.w = fmaf(q0, kv.w, a0.w);
      a1.x = fmaf(q1, kv.x, a1.x); a1.y = fmaf(q1, kv.y, a1.y);
      a1.z = fmaf(q1, kv.z, a1.z); a1.w = fmaf(q1, kv.w, a1.w);
    }
    sc[0][h].x = a0.x * scale; sc[0][h].y = a0.y * scale;
    sc[0][h].z = a0.z * scale; sc[0][h].w = a0.w * scale;
    sc[1][h].x = a1.x * scale; sc[1][h].y = a1.y * scale;
    sc[1][h].z = a1.z * scale; sc[1][h].w = a1.w * scale;
  }

  float m[2][4];
  #pragma unroll
  for (int ti = 0; ti < 2; ++ti)
    #pragma unroll
    for (int h = 0; h < HEADS; ++h) {
      float mm = fmaxf(fmaxf(sc[ti][h].x, sc[ti][h].y), fmaxf(sc[ti][h].z, sc[ti][h].w));
      for (int off = 32; off; off >>= 1) mm = fmaxf(mm, __shfl_xor(mm, off));
      if (lane == 0) s_redm[ti * 4 + h][w] = mm;
    }
  __syncthreads();
  #pragma unroll
  for (int ti = 0; ti < 2; ++ti)
    #pragma unroll
    for (int h = 0; h < HEADS; ++h) {
      const int idx = ti * 4 + h;
      m[ti][h] = fmaxf(fmaxf(s_redm[idx][0], s_redm[idx][1]),
                       fmaxf(s_redm[idx][2], s_redm[idx][3]));
    }

  float inv[2][4];
  #pragma unroll
  for (int ti = 0; ti < 2; ++ti)
    #pragma unroll
    for (int h = 0; h < HEADS; ++h) {
      sc[ti][h].x = __expf(sc[ti][h].x - m[ti][h]);
      sc[ti][h].y = __expf(sc[ti][h].y - m[ti][h]);
      sc[ti][h].z = __expf(sc[ti][h].z - m[ti][h]);
      sc[ti][h].w = __expf(sc[ti][h].w - m[ti][h]);
      float s = sc[ti][h].x + sc[ti][h].y + sc[ti][h].z + sc[ti][h].w;
      for (int off = 32; off; off >>= 1) s += __shfl_xor(s, off);
      if (lane == 0) s_reds[ti * 4 + h][w] = s;
    }
  __syncthreads();
  #pragma unroll
  for (int ti = 0; ti < 2; ++ti)
    #pragma unroll
    for (int h = 0; h < HEADS; ++h) {
      const int idx = ti * 4 + h;
      inv[ti][h] = 0.25f / (s_reds[idx][0] + s_reds[idx][1] + s_reds[idx][2] + s_reds[idx][3]);
    }

  #pragma unroll
  for (int ti = 0; ti < 2; ++ti) {
    float4 o;
    o.x = sc[ti][0].x * inv[ti][0] + sc[ti][1].x * inv[ti][1] +
          sc[ti][2].x * inv[ti][2] + sc[ti][3].x * inv[ti][3];
    o.y = sc[ti][0].y * inv[ti][0] + sc[ti][1].y * inv[ti][1] +
          sc[ti][2].y * inv[ti][2] + sc[ti][3].y * inv[ti][3];
    o.z = sc[ti][0].z * inv[ti][0] + sc[ti][1].z * inv[ti][1] +
          sc[ti][2].z * inv[ti][2] + sc[ti][3].z * inv[ti][3];
    o.w = sc[ti][0].w * inv[ti][0] + sc[ti][1].w * inv[ti][1] +
          sc[ti][2].w * inv[ti][2] + sc[ti][3].w * inv[ti][3];
    ((float4*)(out0 + (i0 + ti) * N))[t] = o;
  }
}

// ---------------- Pairwise MLPs via MFMA, direct global C-store ----------------
// Block: 2 i's x 256 j's. 4 waves; wave handles 64 j (two 32x32 MFMA tiles).
// LDS only 1.5KB -> occupancy VGPR-bound (~6 blocks/CU). C-fragments stored
// straight to out2 (fire-and-forget scalar stores, 2x68B segments per instr).
__global__ __launch_bounds__(256) void k_pair(
    const float* __restrict__ sa_p, const float* __restrict__ sb_ps,
    const float* __restrict__ pb1, const float* __restrict__ pw2, const float* __restrict__ pb2,
    const float* __restrict__ sa_c, const float* __restrict__ sb_cT,
    const float* __restrict__ cb1, const float* __restrict__ cw2, const float* __restrict__ cb2,
    float* __restrict__ out1, float* __restrict__ out2)
{
  __shared__ float s_ap[2][H];
  __shared__ float s_ac[2][64];

  const int t = threadIdx.x;
  const int lane = t & 63, wid = t >> 6;
  const int bid = blockIdx.x;
  const int ip = bid >> 2, jb = bid & 3;
  const int i0 = ip * 2;

  s_ap[t >> 7][t & 127] = sa_p[(i0 + (t >> 7)) * H + (t & 127)] + pb1[t & 127];
  if (t < 128)
    s_ac[t >> 6][t & 63] = sa_c[(i0 + (t >> 6)) * 64 + (t & 63)] + cb1[t & 63];
  __syncthreads();

  const int col = lane & 31;     // MFMA N-col (feature)
  const int hsel = lane >> 5;    // k-subgroup select
  // B fragments straight from global (L2-hot, 8.7KB): lane holds B[k=kc*16+hsel*8+e][col]
  bf16x8 bfrag[8];
  #pragma unroll
  for (int kc = 0; kc < 8; ++kc) {
    #pragma unroll
    for (int e = 0; e < 8; ++e) {
      const int k = kc * 16 + hsel * 8 + e;
      bfrag[kc][e] = f2bf((col < EF) ? pw2[k * EF + col] : 0.f);
    }
  }
  const float pb2c = (col < EF) ? pb2[col] : 0.f;

  const float4* sb4 = (const float4*)sb_ps;

  #pragma unroll
  for (int tt = 0; tt < 2; ++tt) {
    const int Jg = jb * 8 + wid * 2 + tt;   // global 32-j tile index
    f32x16 acc0, acc1;
    #pragma unroll
    for (int r = 0; r < 16; ++r) { acc0[r] = 0.f; acc1[r] = 0.f; }

    #pragma unroll
    for (int kc = 0; kc < 8; ++kc) {
      const int cb = (Jg * 32 + kc * 4 + hsel * 2) * 32 + col;
      const float4 v0 = sb4[cb];        // k = kc*16+hsel*8 .. +3
      const float4 v1 = sb4[cb + 32];   // k = kc*16+hsel*8+4 .. +7
      const float4 c00 = *(const float4*)&s_ap[0][kc * 16 + hsel * 8];
      const float4 c01 = *(const float4*)&s_ap[0][kc * 16 + hsel * 8 + 4];
      const float4 c10 = *(const float4*)&s_ap[1][kc * 16 + hsel * 8];
      const float4 c11 = *(const float4*)&s_ap[1][kc * 16 + hsel * 8 + 4];
      bf16x8 a;
      a[0] = f2bf(fmaxf(c00.x + v0.x, 0.f));
      a[1] = f2bf(fmaxf(c00.y + v0.y, 0.f));
      a[2] = f2bf(fmaxf(c00.z + v0.z, 0.f));
      a[3] = f2bf(fmaxf(c00.w + v0.w, 0.f));
      a[4] = f2bf(fmaxf(c01.x + v1.x, 0.f));
      a[5] = f2bf(fmaxf(c01.y + v1.y, 0.f));
      a[6] = f2bf(fmaxf(c01.z + v1.z, 0.f));
      a[7] = f2bf(fmaxf(c01.w + v1.w, 0.f));
      acc0 = __builtin_amdgcn_mfma_f32_32x32x16_bf16(a, bfrag[kc], acc0, 0, 0, 0);
      a[0] = f2bf(fmaxf(c10.x + v0.x, 0.f));
      a[1] = f2bf(fmaxf(c10.y + v0.y, 0.f));
      a[2] = f2bf(fmaxf(c10.z + v0.z, 0.f));
      a[3] = f2bf(fmaxf(c10.w + v0.w, 0.f));
      a[4] = f2bf(fmaxf(c11.x + v1.x, 0.f));
      a[5] = f2bf(fmaxf(c11.y + v1.y, 0.f));
      a[6] = f2bf(fmaxf(c11.z + v1.z, 0.f));
      a[7] = f2bf(fmaxf(c11.w + v1.w, 0.f));
      acc1 = __builtin_amdgcn_mfma_f32_32x32x16_bf16(a, bfrag[kc], acc1, 0, 0, 0);
    }

    // direct C-store: lane (col<EF) writes rows j = Jg*32 + 4*hsel + (r&3) + 8*(r>>2)
    if (col < EF) {
      const int jbase = Jg * 32 + 4 * hsel;
      float* o20 = out2 + ((size_t)i0 * N + jbase) * EF + col;
      float* o21 = o20 + (size_t)N * EF;
      #pragma unroll
      for (int r = 0; r < 16; ++r) {
        const int off = ((r & 3) + 8 * (r >> 2)) * EF;
        o20[off] = acc0[r] + pb2c;
        o21[off] = acc1[r] + pb2c;
      }
    }
  }

  // classifier path (VALU): thread t owns exactly j = jb*256 + t, both i's
  {
    const int j = jb * 256 + t;
    float ac0 = 0.f, ac1 = 0.f;
    #pragma unroll 8
    for (int k = 0; k < 64; ++k) {
      const float sb = sb_cT[k * N + j];
      const float a0 = s_ac[0][k], a1 = s_ac[1][k];
      const float we = cw2[k];
      ac0 = fmaf(fmaxf(a0 + sb, 0.f), we, ac0);
      ac1 = fmaf(fmaxf(a1 + sb, 0.f), we, ac1);
    }
    const float cb = cb2[0];
    out1[(size_t)i0 * N + j]       = 1.f / (1.f + __expf(-(ac0 + cb)));
    out1[(size_t)(i0 + 1) * N + j] = 1.f / (1.f + __expf(-(ac1 + cb)));
  }
}

extern "C" void kernel_launch(void* const* d_in, const int* in_sizes, int n_in,
                              void* d_out, int out_size, void* d_ws, size_t ws_size,
                              hipStream_t stream) {
  const float* nf  = (const float*)d_in[0];
  const float* ew1 = (const float*)d_in[1];
  const float* eb1 = (const float*)d_in[2];
  const float* ew2 = (const float*)d_in[3];
  const float* eb2 = (const float*)d_in[4];
  const float* ipw = (const float*)d_in[5];
  const float* ipb = (const float*)d_in[6];
  const float* pw1 = (const float*)d_in[7];
  const float* pb1 = (const float*)d_in[8];
  const float* pw2 = (const float*)d_in[9];
  const float* pb2 = (const float*)d_in[10];
  const float* cw1 = (const float*)d_in[11];
  const float* cb1 = (const float*)d_in[12];
  const float* cw2 = (const float*)d_in[13];
  const float* cb2 = (const float*)d_in[14];

  float* ws = (float*)d_ws;
  float* enc   = ws;                 // 1024*128
  float* q     = ws + 131072;        // 1024*128
  float* kkT   = ws + 262144;        // 128*1024 (transposed)
  float* sa_p  = ws + 393216;        // 1024*128
  float* sb_ps = ws + 524288;        // 1024*128 (MFMA-swizzled)
  float* sa_c  = ws + 655360;        // 1024*64
  float* sb_cT = ws + 720896;        // 64*1024 (transposed)

  float* out0 = (float*)d_out;             // attention_weights [1024*1024]
  float* out1 = out0 + N * N;              // edge_probabilities [1024*1024]
  float* out2 = out0 + 2 * N * N;          // predicted_edge_features [1024*1024*17]

  k_encoder<<<N, 128, 0, stream>>>(nf, ew1, eb1, ew2, eb2, enc);
  k_proj<<<N, 256, 0, stream>>>(enc, ipw, ipb, pw1, cw1, q, kkT, sa_p, sb_ps, sa_c, sb_cT);
  k_attn<<<N / 2, 256, 0, stream>>>(q, kkT, out0);
  k_pair<<<512 * 4, 256, 0, stream>>>(sa_p, sb_ps, pb1, pw2, pb2,
                                      sa_c, sb_cT, cb1, cw2, cb2, out1, out2);
}

// Round 9
// 98.096 us; speedup vs baseline: 2.3572x; 1.0260x over previous
//
#include <hip/hip_runtime.h>
#include <hip/hip_bf16.h>

// Problem constants
#define N 1024
#define NF 27
#define EF 17
#define H 128
#define HEADS 4
#define HD 32

typedef __attribute__((ext_vector_type(8))) short bf16x8;
typedef __attribute__((ext_vector_type(16))) float f32x16;

__device__ __forceinline__ short f2bf(float x) {
  return __builtin_bit_cast(short, __float2bfloat16(x));
}
__device__ __forceinline__ unsigned pk2bf(float a, float b) {
  const unsigned lo = (unsigned short)f2bf(a);
  const unsigned hi = (unsigned short)f2bf(b);
  return lo | (hi << 16);
}

// ---------------- Prepack pw2 into MFMA B-fragment order (bf16) ----------------
// w2f[kc*64 + lane] = bf16x8 of B[k=kc*16+hsel*8+e][col], col=lane&31, hsel=lane>>5
__global__ __launch_bounds__(64) void k_prep(const float* __restrict__ pw2,
                                             unsigned short* __restrict__ w2f) {
  const int lane = threadIdx.x;
  const int col = lane & 31, hsel = lane >> 5;
  for (int kc = 0; kc < 8; ++kc)
    for (int e = 0; e < 8; ++e) {
      const int k = kc * 16 + hsel * 8 + e;
      w2f[(kc * 64 + lane) * 8 + e] =
          (unsigned short)((col < EF) ? (unsigned short)f2bf(pw2[k * EF + col]) : 0);
    }
}

// ---------------- Encoder: enc = relu(nf@w1+b1)@w2+b2 ----------------
__global__ __launch_bounds__(128) void k_encoder(
    const float* __restrict__ nf, const float* __restrict__ w1, const float* __restrict__ b1,
    const float* __restrict__ w2, const float* __restrict__ b2, float* __restrict__ enc)
{
  __shared__ float s_nf[NF];
  __shared__ float s_h1[H];
  const int i = blockIdx.x, t = threadIdx.x;
  if (t < NF) s_nf[t] = nf[i * NF + t];
  __syncthreads();
  float h = b1[t];
  #pragma unroll
  for (int f = 0; f < NF; ++f) h = fmaf(s_nf[f], w1[f * H + t], h);
  h = fmaxf(h, 0.f);
  s_h1[t] = h;
  __syncthreads();
  float acc = b2[t];
  #pragma unroll 8
  for (int k = 0; k < H; ++k) acc = fmaf(s_h1[k], w2[k * H + t], acc);
  enc[i * H + t] = acc;
}

// ---------------- Projections ----------------
// sb_p written SWIZZLED into MFMA A-fragment order (see k_pair).
__global__ __launch_bounds__(256) void k_proj(
    const float* __restrict__ enc,
    const float* __restrict__ ipw, const float* __restrict__ ipb,
    const float* __restrict__ pw1, const float* __restrict__ cw1,
    float* __restrict__ q, float* __restrict__ kkT,
    float* __restrict__ sa_p, float* __restrict__ sb_ps,
    float* __restrict__ sa_c, float* __restrict__ sb_cT)
{
  __shared__ float s_e[H];
  const int i = blockIdx.x, t = threadIdx.x;
  if (t < H) s_e[t] = enc[i * H + t];
  __syncthreads();
  for (int c = t; c < 640; c += 256) {
    float acc;
    if (c < 256) {
      acc = ipb[c];
      const float* wcol = ipw + c;
      #pragma unroll 8
      for (int k = 0; k < H; ++k) acc = fmaf(s_e[k], wcol[k * 384], acc);
      if (c < 128) q[i * H + c] = acc;
      else         kkT[(c - 128) * N + i] = acc;   // transposed for coalesced attn reads
    } else if (c < 512) {
      const int cc = (c < 384) ? (c - 256) : (c - 384);
      const float* wcol = (c < 384) ? (pw1 + cc) : (pw1 + 128 * H + cc);
      acc = 0.f;
      #pragma unroll 8
      for (int k = 0; k < H; ++k) acc = fmaf(s_e[k], wcol[k * H], acc);
      if (c < 384) sa_p[i * H + cc] = acc;
      else {
        const int J = i >> 5, jl = i & 31;
        const int kc = cc >> 4, hs = (cc >> 3) & 1, hf = (cc >> 2) & 1, pos = cc & 3;
        sb_ps[(((J * 32 + kc * 4 + hs * 2 + hf) * 32) + jl) * 4 + pos] = acc;
      }
    } else {
      const int cc = (c < 576) ? (c - 512) : (c - 576);
      const float* wcol = (c < 576) ? (cw1 + cc) : (cw1 + 128 * 64 + cc);
      acc = 0.f;
      #pragma unroll 8
      for (int k = 0; k < H; ++k) acc = fmaf(s_e[k], wcol[k * 64], acc);
      if (c < 576) sa_c[i * 64 + cc] = acc;
      else         sb_cT[cc * N + i] = acc;
    }
  }
}

// ---------------- Attention weights: softmax(QK^T/sqrt(hd)) mean over heads ----------------
__global__ __launch_bounds__(256) void k_attn(
    const float* __restrict__ q, const float* __restrict__ kkT, float* __restrict__ out0)
{
  __shared__ float s_q[2][H];
  __shared__ float s_redm[8][4];
  __shared__ float s_reds[8][4];
  const int i0 = blockIdx.x * 2, t = threadIdx.x;
  const int w = t >> 6, lane = t & 63;
  s_q[t >> 7][t & 127] = q[(i0 + (t >> 7)) * H + (t & 127)];
  __syncthreads();

  const float scale = 0.17677669529663687f;  // 1/sqrt(32)
  const float4* kT4 = (const float4*)kkT;    // [128][256] float4 rows
  float4 sc[2][4];

  #pragma unroll
  for (int h = 0; h < HEADS; ++h) {
    float4 a0 = {0.f, 0.f, 0.f, 0.f}, a1 = {0.f, 0.f, 0.f, 0.f};
    #pragma unroll 8
    for (int d = 0; d < HD; ++d) {
      const float4 kv = kT4[(h * HD + d) * 256 + t];
      const float q0 = s_q[0][h * HD + d], q1 = s_q[1][h * HD + d];
      a0.x = fmaf(q0, kv.x, a0.x); a0.y = fmaf(q0, kv.y, a0.y);
      a0.z = fmaf(q0, kv.z, a0.z); a0.w = fmaf(q0, kv.w, a0.w);
      a1.x = fmaf(q1, kv.x, a1.x); a1.y = fmaf(q1, kv.y, a1.y);
      a1.z = fmaf(q1, kv.z, a1.z); a1.w = fmaf(q1, kv.w, a1.w);
    }
    sc[0][h].x = a0.x * scale; sc[0][h].y = a0.y * scale;
    sc[0][h].z = a0.z * scale; sc[0][h].w = a0.w * scale;
    sc[1][h].x = a1.x * scale; sc[1][h].y = a1.y * scale;
    sc[1][h].z = a1.z * scale; sc[1][h].w = a1.w * scale;
  }

  float m[2][4];
  #pragma unroll
  for (int ti = 0; ti < 2; ++ti)
    #pragma unroll
    for (int h = 0; h < HEADS; ++h) {
      float mm = fmaxf(fmaxf(sc[ti][h].x, sc[ti][h].y), fmaxf(sc[ti][h].z, sc[ti][h].w));
      for (int off = 32; off; off >>= 1) mm = fmaxf(mm, __shfl_xor(mm, off));
      if (lane == 0) s_redm[ti * 4 + h][w] = mm;
    }
  __syncthreads();
  #pragma unroll
  for (int ti = 0; ti < 2; ++ti)
    #pragma unroll
    for (int h = 0; h < HEADS; ++h) {
      const int idx = ti * 4 + h;
      m[ti][h] = fmaxf(fmaxf(s_redm[idx][0], s_redm[idx][1]),
                       fmaxf(s_redm[idx][2], s_redm[idx][3]));
    }

  float inv[2][4];
  #pragma unroll
  for (int ti = 0; ti < 2; ++ti)
    #pragma unroll
    for (int h = 0; h < HEADS; ++h) {
      sc[ti][h].x = __expf(sc[ti][h].x - m[ti][h]);
      sc[ti][h].y = __expf(sc[ti][h].y - m[ti][h]);
      sc[ti][h].z = __expf(sc[ti][h].z - m[ti][h]);
      sc[ti][h].w = __expf(sc[ti][h].w - m[ti][h]);
      float s = sc[ti][h].x + sc[ti][h].y + sc[ti][h].z + sc[ti][h].w;
      for (int off = 32; off; off >>= 1) s += __shfl_xor(s, off);
      if (lane == 0) s_reds[ti * 4 + h][w] = s;
    }
  __syncthreads();
  #pragma unroll
  for (int ti = 0; ti < 2; ++ti)
    #pragma unroll
    for (int h = 0; h < HEADS; ++h) {
      const int idx = ti * 4 + h;
      inv[ti][h] = 0.25f / (s_reds[idx][0] + s_reds[idx][1] + s_reds[idx][2] + s_reds[idx][3]);
    }

  #pragma unroll
  for (int ti = 0; ti < 2; ++ti) {
    float4 o;
    o.x = sc[ti][0].x * inv[ti][0] + sc[ti][1].x * inv[ti][1] +
          sc[ti][2].x * inv[ti][2] + sc[ti][3].x * inv[ti][3];
    o.y = sc[ti][0].y * inv[ti][0] + sc[ti][1].y * inv[ti][1] +
          sc[ti][2].y * inv[ti][2] + sc[ti][3].y * inv[ti][3];
    o.z = sc[ti][0].z * inv[ti][0] + sc[ti][1].z * inv[ti][1] +
          sc[ti][2].z * inv[ti][2] + sc[ti][3].z * inv[ti][3];
    o.w = sc[ti][0].w * inv[ti][0] + sc[ti][1].w * inv[ti][1] +
          sc[ti][2].w * inv[ti][2] + sc[ti][3].w * inv[ti][3];
    ((float4*)(out0 + (i0 + ti) * N))[t] = o;
  }
}

// ---------------- Edge classifier (separate, float4-coalesced) ----------------
// Block = 2 i's x 1024 j; thread t owns j = 4t..4t+3.
__global__ __launch_bounds__(256) void k_cls(
    const float* __restrict__ sa_c, const float* __restrict__ sb_cT,
    const float* __restrict__ cb1, const float* __restrict__ cw2, const float* __restrict__ cb2,
    float* __restrict__ out1)
{
  __shared__ float s_ac[2][64];
  const int i0 = blockIdx.x * 2, t = threadIdx.x;
  if (t < 128)
    s_ac[t >> 6][t & 63] = sa_c[(i0 + (t >> 6)) * 64 + (t & 63)] + cb1[t & 63];
  __syncthreads();

  const float4* sbc4 = (const float4*)sb_cT;   // [64][256 float4]
  float4 ac0 = {0.f, 0.f, 0.f, 0.f}, ac1 = {0.f, 0.f, 0.f, 0.f};
  #pragma unroll 4
  for (int k = 0; k < 64; ++k) {
    const float4 sb = sbc4[k * 256 + t];
    const float a0 = s_ac[0][k], a1 = s_ac[1][k];
    const float we = cw2[k];
    ac0.x = fmaf(fmaxf(a0 + sb.x, 0.f), we, ac0.x);
    ac0.y = fmaf(fmaxf(a0 + sb.y, 0.f), we, ac0.y);
    ac0.z = fmaf(fmaxf(a0 + sb.z, 0.f), we, ac0.z);
    ac0.w = fmaf(fmaxf(a0 + sb.w, 0.f), we, ac0.w);
    ac1.x = fmaf(fmaxf(a1 + sb.x, 0.f), we, ac1.x);
    ac1.y = fmaf(fmaxf(a1 + sb.y, 0.f), we, ac1.y);
    ac1.z = fmaf(fmaxf(a1 + sb.z, 0.f), we, ac1.z);
    ac1.w = fmaf(fmaxf(a1 + sb.w, 0.f), we, ac1.w);
  }
  const float cb = cb2[0];
  float4 o0, o1;
  o0.x = 1.f / (1.f + __expf(-(ac0.x + cb)));
  o0.y = 1.f / (1.f + __expf(-(ac0.y + cb)));
  o0.z = 1.f / (1.f + __expf(-(ac0.z + cb)));
  o0.w = 1.f / (1.f + __expf(-(ac0.w + cb)));
  o1.x = 1.f / (1.f + __expf(-(ac1.x + cb)));
  o1.y = 1.f / (1.f + __expf(-(ac1.y + cb)));
  o1.z = 1.f / (1.f + __expf(-(ac1.z + cb)));
  o1.w = 1.f / (1.f + __expf(-(ac1.w + cb)));
  ((float4*)(out1 + (size_t)i0 * N))[t] = o0;
  ((float4*)(out1 + (size_t)(i0 + 1) * N))[t] = o1;
}

// ---------------- Pairwise edge-feature MLP via MFMA ----------------
// Block: 1 i x 256 j (4 waves x two 32x32 tiles). Minimal registers:
// acc = 16 AGPR, bfrag from prepacked w2f (8 x 16B coalesced loads).
__global__ __launch_bounds__(256) void k_pair(
    const float* __restrict__ sa_p, const float* __restrict__ sb_ps,
    const float* __restrict__ pb1, const unsigned short* __restrict__ w2f,
    const float* __restrict__ pb2, float* __restrict__ out2)
{
  __shared__ float s_ap[H];

  const int t = threadIdx.x;
  const int lane = t & 63, wid = t >> 6;
  const int bid = blockIdx.x;
  const int i = bid >> 2, jb = bid & 3;

  if (t < H) s_ap[t] = sa_p[i * H + t] + pb1[t];
  __syncthreads();

  const int col = lane & 31;     // MFMA N-col (feature)
  const int hsel = lane >> 5;    // k-subgroup select
  const bf16x8* w2f8 = (const bf16x8*)w2f;
  bf16x8 bfrag[8];
  #pragma unroll
  for (int kc = 0; kc < 8; ++kc) bfrag[kc] = w2f8[kc * 64 + lane];
  const float pb2c = (col < EF) ? pb2[col] : 0.f;

  const float4* sb4 = (const float4*)sb_ps;

  #pragma unroll
  for (int tt = 0; tt < 2; ++tt) {
    const int Jg = jb * 8 + wid * 2 + tt;   // global 32-j tile index
    f32x16 acc;
    #pragma unroll
    for (int r = 0; r < 16; ++r) acc[r] = 0.f;

    #pragma unroll
    for (int kc = 0; kc < 8; ++kc) {
      const int cb = (Jg * 32 + kc * 4 + hsel * 2) * 32 + col;
      const float4 v0 = sb4[cb];        // k = kc*16+hsel*8 .. +3
      const float4 v1 = sb4[cb + 32];   // k = kc*16+hsel*8+4 .. +7
      const float4 c0 = *(const float4*)&s_ap[kc * 16 + hsel * 8];
      const float4 c1 = *(const float4*)&s_ap[kc * 16 + hsel * 8 + 4];
      union { bf16x8 v8; unsigned u[4]; } au;
      au.u[0] = pk2bf(fmaxf(c0.x + v0.x, 0.f), fmaxf(c0.y + v0.y, 0.f));
      au.u[1] = pk2bf(fmaxf(c0.z + v0.z, 0.f), fmaxf(c0.w + v0.w, 0.f));
      au.u[2] = pk2bf(fmaxf(c1.x + v1.x, 0.f), fmaxf(c1.y + v1.y, 0.f));
      au.u[3] = pk2bf(fmaxf(c1.z + v1.z, 0.f), fmaxf(c1.w + v1.w, 0.f));
      acc = __builtin_amdgcn_mfma_f32_32x32x16_bf16(au.v8, bfrag[kc], acc, 0, 0, 0);
    }

    // direct C-store: lane (col<EF) writes rows j = Jg*32 + 4*hsel + (r&3) + 8*(r>>2)
    if (col < EF) {
      const int jbase = Jg * 32 + 4 * hsel;
      float* o2 = out2 + ((size_t)i * N + jbase) * EF + col;
      #pragma unroll
      for (int r = 0; r < 16; ++r) {
        const int off = ((r & 3) + 8 * (r >> 2)) * EF;
        o2[off] = acc[r] + pb2c;
      }
    }
  }
}

extern "C" void kernel_launch(void* const* d_in, const int* in_sizes, int n_in,
                              void* d_out, int out_size, void* d_ws, size_t ws_size,
                              hipStream_t stream) {
  const float* nf  = (const float*)d_in[0];
  const float* ew1 = (const float*)d_in[1];
  const float* eb1 = (const float*)d_in[2];
  const float* ew2 = (const float*)d_in[3];
  const float* eb2 = (const float*)d_in[4];
  const float* ipw = (const float*)d_in[5];
  const float* ipb = (const float*)d_in[6];
  const float* pw1 = (const float*)d_in[7];
  const float* pb1 = (const float*)d_in[8];
  const float* pw2 = (const float*)d_in[9];
  const float* pb2 = (const float*)d_in[10];
  const float* cw1 = (const float*)d_in[11];
  const float* cb1 = (const float*)d_in[12];
  const float* cw2 = (const float*)d_in[13];
  const float* cb2 = (const float*)d_in[14];

  float* ws = (float*)d_ws;
  float* enc   = ws;                 // 1024*128
  float* q     = ws + 131072;        // 1024*128
  float* kkT   = ws + 262144;        // 128*1024 (transposed)
  float* sa_p  = ws + 393216;        // 1024*128
  float* sb_ps = ws + 524288;        // 1024*128 (MFMA-swizzled)
  float* sa_c  = ws + 655360;        // 1024*64
  float* sb_cT = ws + 720896;        // 64*1024 (transposed)
  unsigned short* w2f = (unsigned short*)(ws + 786432);  // 8*64*8 bf16

  float* out0 = (float*)d_out;             // attention_weights [1024*1024]
  float* out1 = out0 + N * N;              // edge_probabilities [1024*1024]
  float* out2 = out0 + 2 * N * N;          // predicted_edge_features [1024*1024*17]

  k_prep<<<1, 64, 0, stream>>>(pw2, w2f);
  k_encoder<<<N, 128, 0, stream>>>(nf, ew1, eb1, ew2, eb2, enc);
  k_proj<<<N, 256, 0, stream>>>(enc, ipw, ipb, pw1, cw1, q, kkT, sa_p, sb_ps, sa_c, sb_cT);
  k_attn<<<N / 2, 256, 0, stream>>>(q, kkT, out0);
  k_cls<<<N / 2, 256, 0, stream>>>(sa_c, sb_cT, cb1, cw2, cb2, out1);
  k_pair<<<N * 4, 256, 0, stream>>>(sa_p, sb_ps, pb1, w2f, pb2, out2);
}

// Round 10
// 93.530 us; speedup vs baseline: 2.4723x; 1.0488x over previous
//
#include <hip/hip_runtime.h>
#include <hip/hip_bf16.h>

// Problem constants
#define N 1024
#define NF 27
#define EF 17
#define H 128
#define HEADS 4
#define HD 32

typedef __attribute__((ext_vector_type(8))) short bf16x8;
typedef __attribute__((ext_vector_type(16))) float f32x16;

__device__ __forceinline__ short f2bf(float x) {
  return __builtin_bit_cast(short, __float2bfloat16(x));
}
__device__ __forceinline__ unsigned pk2bf(float a, float b) {
  const unsigned lo = (unsigned short)f2bf(a);
  const unsigned hi = (unsigned short)f2bf(b);
  return lo | (hi << 16);
}

// ---------------- Prepack pw2 into MFMA B-fragment order (bf16) ----------------
// w2f[kc*64 + lane] = bf16x8 of B[k=kc*16+hsel*8+e][col], col=lane&31, hsel=lane>>5
__global__ __launch_bounds__(64) void k_prep(const float* __restrict__ pw2,
                                             unsigned short* __restrict__ w2f) {
  const int lane = threadIdx.x;
  const int col = lane & 31, hsel = lane >> 5;
  for (int kc = 0; kc < 8; ++kc)
    for (int e = 0; e < 8; ++e) {
      const int k = kc * 16 + hsel * 8 + e;
      w2f[(kc * 64 + lane) * 8 + e] =
          (unsigned short)((col < EF) ? (unsigned short)f2bf(pw2[k * EF + col]) : 0);
    }
}

// ---------------- Encoder: enc = relu(nf@w1+b1)@w2+b2 ----------------
__global__ __launch_bounds__(128) void k_encoder(
    const float* __restrict__ nf, const float* __restrict__ w1, const float* __restrict__ b1,
    const float* __restrict__ w2, const float* __restrict__ b2, float* __restrict__ enc)
{
  __shared__ float s_nf[NF];
  __shared__ float s_h1[H];
  const int i = blockIdx.x, t = threadIdx.x;
  if (t < NF) s_nf[t] = nf[i * NF + t];
  __syncthreads();
  float h = b1[t];
  #pragma unroll
  for (int f = 0; f < NF; ++f) h = fmaf(s_nf[f], w1[f * H + t], h);
  h = fmaxf(h, 0.f);
  s_h1[t] = h;
  __syncthreads();
  float acc = b2[t];
  #pragma unroll 8
  for (int k = 0; k < H; ++k) acc = fmaf(s_h1[k], w2[k * H + t], acc);
  enc[i * H + t] = acc;
}

// ---------------- Projections ----------------
// sb_p written SWIZZLED into MFMA A-fragment order (see k_pair).
__global__ __launch_bounds__(256) void k_proj(
    const float* __restrict__ enc,
    const float* __restrict__ ipw, const float* __restrict__ ipb,
    const float* __restrict__ pw1, const float* __restrict__ cw1,
    float* __restrict__ q, float* __restrict__ kkT,
    float* __restrict__ sa_p, float* __restrict__ sb_ps,
    float* __restrict__ sa_c, float* __restrict__ sb_cT)
{
  __shared__ float s_e[H];
  const int i = blockIdx.x, t = threadIdx.x;
  if (t < H) s_e[t] = enc[i * H + t];
  __syncthreads();
  for (int c = t; c < 640; c += 256) {
    float acc;
    if (c < 256) {
      acc = ipb[c];
      const float* wcol = ipw + c;
      #pragma unroll 8
      for (int k = 0; k < H; ++k) acc = fmaf(s_e[k], wcol[k * 384], acc);
      if (c < 128) q[i * H + c] = acc;
      else         kkT[(c - 128) * N + i] = acc;   // transposed for coalesced attn reads
    } else if (c < 512) {
      const int cc = (c < 384) ? (c - 256) : (c - 384);
      const float* wcol = (c < 384) ? (pw1 + cc) : (pw1 + 128 * H + cc);
      acc = 0.f;
      #pragma unroll 8
      for (int k = 0; k < H; ++k) acc = fmaf(s_e[k], wcol[k * H], acc);
      if (c < 384) sa_p[i * H + cc] = acc;
      else {
        const int J = i >> 5, jl = i & 31;
        const int kc = cc >> 4, hs = (cc >> 3) & 1, hf = (cc >> 2) & 1, pos = cc & 3;
        sb_ps[(((J * 32 + kc * 4 + hs * 2 + hf) * 32) + jl) * 4 + pos] = acc;
      }
    } else {
      const int cc = (c < 576) ? (c - 512) : (c - 576);
      const float* wcol = (c < 576) ? (cw1 + cc) : (cw1 + 128 * 64 + cc);
      acc = 0.f;
      #pragma unroll 8
      for (int k = 0; k < H; ++k) acc = fmaf(s_e[k], wcol[k * 64], acc);
      if (c < 576) sa_c[i * 64 + cc] = acc;
      else         sb_cT[cc * N + i] = acc;
    }
  }
}

// ---------------- Attention weights: softmax(QK^T/sqrt(hd)) mean over heads ----------------
__global__ __launch_bounds__(256) void k_attn(
    const float* __restrict__ q, const float* __restrict__ kkT, float* __restrict__ out0)
{
  __shared__ float s_q[2][H];
  __shared__ float s_redm[8][4];
  __shared__ float s_reds[8][4];
  const int i0 = blockIdx.x * 2, t = threadIdx.x;
  const int w = t >> 6, lane = t & 63;
  s_q[t >> 7][t & 127] = q[(i0 + (t >> 7)) * H + (t & 127)];
  __syncthreads();

  const float scale = 0.17677669529663687f;  // 1/sqrt(32)
  const float4* kT4 = (const float4*)kkT;    // [128][256] float4 rows
  float4 sc[2][4];

  #pragma unroll
  for (int h = 0; h < HEADS; ++h) {
    float4 a0 = {0.f, 0.f, 0.f, 0.f}, a1 = {0.f, 0.f, 0.f, 0.f};
    #pragma unroll 8
    for (int d = 0; d < HD; ++d) {
      const float4 kv = kT4[(h * HD + d) * 256 + t];
      const float q0 = s_q[0][h * HD + d], q1 = s_q[1][h * HD + d];
      a0.x = fmaf(q0, kv.x, a0.x); a0.y = fmaf(q0, kv.y, a0.y);
      a0.z = fmaf(q0, kv.z, a0.z); a0.w = fmaf(q0, kv.w, a0.w);
      a1.x = fmaf(q1, kv.x, a1.x); a1.y = fmaf(q1, kv.y, a1.y);
      a1.z = fmaf(q1, kv.z, a1.z); a1.w = fmaf(q1, kv.w, a1.w);
    }
    sc[0][h].x = a0.x * scale; sc[0][h].y = a0.y * scale;
    sc[0][h].z = a0.z * scale; sc[0][h].w = a0.w * scale;
    sc[1][h].x = a1.x * scale; sc[1][h].y = a1.y * scale;
    sc[1][h].z = a1.z * scale; sc[1][h].w = a1.w * scale;
  }

  float m[2][4];
  #pragma unroll
  for (int ti = 0; ti < 2; ++ti)
    #pragma unroll
    for (int h = 0; h < HEADS; ++h) {
      float mm = fmaxf(fmaxf(sc[ti][h].x, sc[ti][h].y), fmaxf(sc[ti][h].z, sc[ti][h].w));
      for (int off = 32; off; off >>= 1) mm = fmaxf(mm, __shfl_xor(mm, off));
      if (lane == 0) s_redm[ti * 4 + h][w] = mm;
    }
  __syncthreads();
  #pragma unroll
  for (int ti = 0; ti < 2; ++ti)
    #pragma unroll
    for (int h = 0; h < HEADS; ++h) {
      const int idx = ti * 4 + h;
      m[ti][h] = fmaxf(fmaxf(s_redm[idx][0], s_redm[idx][1]),
                       fmaxf(s_redm[idx][2], s_redm[idx][3]));
    }

  float inv[2][4];
  #pragma unroll
  for (int ti = 0; ti < 2; ++ti)
    #pragma unroll
    for (int h = 0; h < HEADS; ++h) {
      sc[ti][h].x = __expf(sc[ti][h].x - m[ti][h]);
      sc[ti][h].y = __expf(sc[ti][h].y - m[ti][h]);
      sc[ti][h].z = __expf(sc[ti][h].z - m[ti][h]);
      sc[ti][h].w = __expf(sc[ti][h].w - m[ti][h]);
      float s = sc[ti][h].x + sc[ti][h].y + sc[ti][h].z + sc[ti][h].w;
      for (int off = 32; off; off >>= 1) s += __shfl_xor(s, off);
      if (lane == 0) s_reds[ti * 4 + h][w] = s;
    }
  __syncthreads();
  #pragma unroll
  for (int ti = 0; ti < 2; ++ti)
    #pragma unroll
    for (int h = 0; h < HEADS; ++h) {
      const int idx = ti * 4 + h;
      inv[ti][h] = 0.25f / (s_reds[idx][0] + s_reds[idx][1] + s_reds[idx][2] + s_reds[idx][3]);
    }

  #pragma unroll
  for (int ti = 0; ti < 2; ++ti) {
    float4 o;
    o.x = sc[ti][0].x * inv[ti][0] + sc[ti][1].x * inv[ti][1] +
          sc[ti][2].x * inv[ti][2] + sc[ti][3].x * inv[ti][3];
    o.y = sc[ti][0].y * inv[ti][0] + sc[ti][1].y * inv[ti][1] +
          sc[ti][2].y * inv[ti][2] + sc[ti][3].y * inv[ti][3];
    o.z = sc[ti][0].z * inv[ti][0] + sc[ti][1].z * inv[ti][1] +
          sc[ti][2].z * inv[ti][2] + sc[ti][3].z * inv[ti][3];
    o.w = sc[ti][0].w * inv[ti][0] + sc[ti][1].w * inv[ti][1] +
          sc[ti][2].w * inv[ti][2] + sc[ti][3].w * inv[ti][3];
    ((float4*)(out0 + (i0 + ti) * N))[t] = o;
  }
}

// ---------------- Edge classifier (separate, float4-coalesced) ----------------
__global__ __launch_bounds__(256) void k_cls(
    const float* __restrict__ sa_c, const float* __restrict__ sb_cT,
    const float* __restrict__ cb1, const float* __restrict__ cw2, const float* __restrict__ cb2,
    float* __restrict__ out1)
{
  __shared__ float s_ac[2][64];
  const int i0 = blockIdx.x * 2, t = threadIdx.x;
  if (t < 128)
    s_ac[t >> 6][t & 63] = sa_c[(i0 + (t >> 6)) * 64 + (t & 63)] + cb1[t & 63];
  __syncthreads();

  const float4* sbc4 = (const float4*)sb_cT;   // [64][256 float4]
  float4 ac0 = {0.f, 0.f, 0.f, 0.f}, ac1 = {0.f, 0.f, 0.f, 0.f};
  #pragma unroll 4
  for (int k = 0; k < 64; ++k) {
    const float4 sb = sbc4[k * 256 + t];
    const float a0 = s_ac[0][k], a1 = s_ac[1][k];
    const float we = cw2[k];
    ac0.x = fmaf(fmaxf(a0 + sb.x, 0.f), we, ac0.x);
    ac0.y = fmaf(fmaxf(a0 + sb.y, 0.f), we, ac0.y);
    ac0.z = fmaf(fmaxf(a0 + sb.z, 0.f), we, ac0.z);
    ac0.w = fmaf(fmaxf(a0 + sb.w, 0.f), we, ac0.w);
    ac1.x = fmaf(fmaxf(a1 + sb.x, 0.f), we, ac1.x);
    ac1.y = fmaf(fmaxf(a1 + sb.y, 0.f), we, ac1.y);
    ac1.z = fmaf(fmaxf(a1 + sb.z, 0.f), we, ac1.z);
    ac1.w = fmaf(fmaxf(a1 + sb.w, 0.f), we, ac1.w);
  }
  const float cb = cb2[0];
  float4 o0, o1;
  o0.x = 1.f / (1.f + __expf(-(ac0.x + cb)));
  o0.y = 1.f / (1.f + __expf(-(ac0.y + cb)));
  o0.z = 1.f / (1.f + __expf(-(ac0.z + cb)));
  o0.w = 1.f / (1.f + __expf(-(ac0.w + cb)));
  o1.x = 1.f / (1.f + __expf(-(ac1.x + cb)));
  o1.y = 1.f / (1.f + __expf(-(ac1.y + cb)));
  o1.z = 1.f / (1.f + __expf(-(ac1.z + cb)));
  o1.w = 1.f / (1.f + __expf(-(ac1.w + cb)));
  ((float4*)(out1 + (size_t)i0 * N))[t] = o0;
  ((float4*)(out1 + (size_t)(i0 + 1) * N))[t] = o1;
}

// ---------------- Pairwise edge-feature MLP via MFMA, 32x32 2-D tiles ----------------
// Block = 32 i x 32 j. Grid 1024 = 4 blocks/CU, ALL resident (LDS 32KB -> 5/CU max).
// sb j-tile (16KB) + ap i-tile (16KB, bias folded) staged in LDS once; each of
// 4 waves computes 8 i's x one 32x32xK=128 MFMA tile from LDS operands.
__global__ __launch_bounds__(256) void k_pair(
    const float* __restrict__ sa_p, const float* __restrict__ sb_ps,
    const float* __restrict__ pb1, const unsigned short* __restrict__ w2f,
    const float* __restrict__ pb2, float* __restrict__ out2)
{
  __shared__ float4 s_sb[1024];      // 16 KB: sb fragments for this j-tile
  __shared__ float s_ap[32][H];      // 16 KB: ap rows (bias folded)

  const int t = threadIdx.x;
  const int lane = t & 63, wid = t >> 6;
  const int It = blockIdx.x >> 5;    // i-tile (32 i's)
  const int J  = blockIdx.x & 31;    // j-tile (32 j's)
  const int i0 = It * 32;

  // stage sb tile: float4 indices [J*1024, J*1024+1024)
  const float4* g_sb = ((const float4*)sb_ps) + J * 1024;
  #pragma unroll
  for (int c = t; c < 1024; c += 256) s_sb[c] = g_sb[c];
  // stage ap tile + bias
  const float4* g_ap = (const float4*)(sa_p + i0 * H);
  const float4* pb14 = (const float4*)pb1;
  #pragma unroll
  for (int c = t; c < 1024; c += 256) {
    float4 v = g_ap[c];
    const float4 b = pb14[c & 31];
    v.x += b.x; v.y += b.y; v.z += b.z; v.w += b.w;
    ((float4*)&s_ap[c >> 5][0])[c & 31] = v;
  }

  const int col = lane & 31, hsel = lane >> 5;
  const bf16x8* w2f8 = (const bf16x8*)w2f;
  bf16x8 bfrag[8];
  #pragma unroll
  for (int kc = 0; kc < 8; ++kc) bfrag[kc] = w2f8[kc * 64 + lane];
  const float pb2c = (col < EF) ? pb2[col] : 0.f;
  __syncthreads();

  #pragma unroll 2
  for (int ii = 0; ii < 8; ++ii) {
    const int il = wid * 8 + ii;
    f32x16 acc;
    #pragma unroll
    for (int r = 0; r < 16; ++r) acc[r] = 0.f;

    #pragma unroll
    for (int kc = 0; kc < 8; ++kc) {
      const int cl = (kc * 4 + hsel * 2) * 32 + col;
      const float4 v0 = s_sb[cl];        // k = kc*16+hsel*8 .. +3
      const float4 v1 = s_sb[cl + 32];   // k = kc*16+hsel*8+4 .. +7
      const float4 c0 = *(const float4*)&s_ap[il][kc * 16 + hsel * 8];
      const float4 c1 = *(const float4*)&s_ap[il][kc * 16 + hsel * 8 + 4];
      union { bf16x8 v8; unsigned u[4]; } au;
      au.u[0] = pk2bf(fmaxf(c0.x + v0.x, 0.f), fmaxf(c0.y + v0.y, 0.f));
      au.u[1] = pk2bf(fmaxf(c0.z + v0.z, 0.f), fmaxf(c0.w + v0.w, 0.f));
      au.u[2] = pk2bf(fmaxf(c1.x + v1.x, 0.f), fmaxf(c1.y + v1.y, 0.f));
      au.u[3] = pk2bf(fmaxf(c1.z + v1.z, 0.f), fmaxf(c1.w + v1.w, 0.f));
      acc = __builtin_amdgcn_mfma_f32_32x32x16_bf16(au.v8, bfrag[kc], acc, 0, 0, 0);
    }

    // C-store: lane (col<EF) writes rows j = J*32 + 4*hsel + (r&3) + 8*(r>>2)
    if (col < EF) {
      const int jbase = J * 32 + 4 * hsel;
      float* o2 = out2 + ((size_t)(i0 + il) * N + jbase) * EF + col;
      #pragma unroll
      for (int r = 0; r < 16; ++r) {
        const int off = ((r & 3) + 8 * (r >> 2)) * EF;
        o2[off] = acc[r] + pb2c;
      }
    }
  }
}

extern "C" void kernel_launch(void* const* d_in, const int* in_sizes, int n_in,
                              void* d_out, int out_size, void* d_ws, size_t ws_size,
                              hipStream_t stream) {
  const float* nf  = (const float*)d_in[0];
  const float* ew1 = (const float*)d_in[1];
  const float* eb1 = (const float*)d_in[2];
  const float* ew2 = (const float*)d_in[3];
  const float* eb2 = (const float*)d_in[4];
  const float* ipw = (const float*)d_in[5];
  const float* ipb = (const float*)d_in[6];
  const float* pw1 = (const float*)d_in[7];
  const float* pb1 = (const float*)d_in[8];
  const float* pw2 = (const float*)d_in[9];
  const float* pb2 = (const float*)d_in[10];
  const float* cw1 = (const float*)d_in[11];
  const float* cb1 = (const float*)d_in[12];
  const float* cw2 = (const float*)d_in[13];
  const float* cb2 = (const float*)d_in[14];

  float* ws = (float*)d_ws;
  float* enc   = ws;                 // 1024*128
  float* q     = ws + 131072;        // 1024*128
  float* kkT   = ws + 262144;        // 128*1024 (transposed)
  float* sa_p  = ws + 393216;        // 1024*128
  float* sb_ps = ws + 524288;        // 1024*128 (MFMA-swizzled)
  float* sa_c  = ws + 655360;        // 1024*64
  float* sb_cT = ws + 720896;        // 64*1024 (transposed)
  unsigned short* w2f = (unsigned short*)(ws + 786432);  // 8*64*8 bf16

  float* out0 = (float*)d_out;             // attention_weights [1024*1024]
  float* out1 = out0 + N * N;              // edge_probabilities [1024*1024]
  float* out2 = out0 + 2 * N * N;          // predicted_edge_features [1024*1024*17]

  k_prep<<<1, 64, 0, stream>>>(pw2, w2f);
  k_encoder<<<N, 128, 0, stream>>>(nf, ew1, eb1, ew2, eb2, enc);
  k_proj<<<N, 256, 0, stream>>>(enc, ipw, ipb, pw1, cw1, q, kkT, sa_p, sb_ps, sa_c, sb_cT);
  k_attn<<<N / 2, 256, 0, stream>>>(q, kkT, out0);
  k_cls<<<N / 2, 256, 0, stream>>>(sa_c, sb_cT, cb1, cw2, cb2, out1);
  k_pair<<<1024, 256, 0, stream>>>(sa_p, sb_ps, pb1, w2f, pb2, out2);
}